// Round 1
// baseline (1105.717 us; speedup 1.0000x reference)
//
#include <hip/hip_runtime.h>
#include <math.h>

#define TM 64
#define TN 64
#define KT 32

// Generic tiled f32 GEMM: C[row, n] = epilogue( sum_k A[row,k] * W[k,n] )
// AMODE 0: A dense [rows, K] (row stride = K)
// AMODE 1: A framed from signal: A[(b,t), k] = sig[b*Lsig + 160*t + k], 0 past end
// AMODE 2: A = GLN-normalized aux: g0[k]*(aux-mean[b])*rstd[b]+g1[k], 0 for t>=len[b]
// EPI 0: C = acc + bias[n]
// EPI 1: C = (t<len[b]) ? relu(acc + bias[n]) : 0
// EPI 2: C = tanh( relu(acc + rowvec[b,n]) * g0[n] + g1[n] )
// EPI 4: C = Aold[row,n] + tanh(acc + rowvec[b,n])       (N must be 256)
template<int AMODE, int EPI>
__global__ __launch_bounds__(256) void gemm_k(
    const float* __restrict__ Asrc, const float* __restrict__ W, int ldw,
    const float* __restrict__ bias, float* __restrict__ C,
    const float* __restrict__ Aold, const float* __restrict__ rowvec,
    const float* __restrict__ g0, const float* __restrict__ g1,
    const float* __restrict__ stat0, const float* __restrict__ stat1,
    const int* __restrict__ lens,
    int Trows, int K, int N, int Lsig)
{
    __shared__ float As[TM][KT + 4];   // [m][k], pad to 36 to keep banks spread
    __shared__ float Bs[KT][TN];       // [k][n]
    const int b   = blockIdx.z;
    const int m0  = blockIdx.y * TM;
    const int n0  = blockIdx.x * TN;
    const int tid = threadIdx.x;
    const int tx = tid & 15, ty = tid >> 4;   // compute mapping: 4x4 at (ty*4, tx*4)
    const int lm = tid >> 3, kq = tid & 7;    // A loader: rows lm, lm+32; k = kq*4
    const int nq = tid & 15, kb = tid >> 4;   // B loader: n = nq*4; k = kb, kb+16

    int len = 0;
    if (AMODE == 2 || EPI == 1) len = lens[b];
    float mean = 0.f, rstd = 0.f;
    if (AMODE == 2) { mean = stat0[b]; rstd = stat1[b]; }

    const long rowbase = (long)b * Trows + m0;
    float acc[4][4] = {};

    for (int k0 = 0; k0 < K; k0 += KT) {
        // ---- A tile ----
        #pragma unroll
        for (int rr = 0; rr < 2; ++rr) {
            int m = lm + rr * 32;
            int row = m0 + m;
            float4 v = make_float4(0.f, 0.f, 0.f, 0.f);
            if (row < Trows) {
                if (AMODE == 0) {
                    v = *(const float4*)(Asrc + (rowbase + m) * (long)K + k0 + kq * 4);
                } else if (AMODE == 1) {
                    int kk0 = 160 * row + k0 + kq * 4;
                    const float* p = Asrc + (long)b * Lsig + kk0;
                    if (kk0 + 3 < Lsig) {
                        v = *(const float4*)p;
                    } else {
                        float t0_ = (kk0 + 0 < Lsig) ? p[0] : 0.f;
                        float t1_ = (kk0 + 1 < Lsig) ? p[1] : 0.f;
                        float t2_ = (kk0 + 2 < Lsig) ? p[2] : 0.f;
                        float t3_ = (kk0 + 3 < Lsig) ? p[3] : 0.f;
                        v = make_float4(t0_, t1_, t2_, t3_);
                    }
                } else { // AMODE 2
                    if (row < len) {
                        float4 u = *(const float4*)(Asrc + (rowbase + m) * 256L + k0 + kq * 4);
                        int k = k0 + kq * 4;
                        v.x = g0[k+0] * (u.x - mean) * rstd + g1[k+0];
                        v.y = g0[k+1] * (u.y - mean) * rstd + g1[k+1];
                        v.z = g0[k+2] * (u.z - mean) * rstd + g1[k+2];
                        v.w = g0[k+3] * (u.w - mean) * rstd + g1[k+3];
                    }
                }
            }
            *(float4*)&As[m][kq * 4] = v;
        }
        // ---- B tile ----
        #pragma unroll
        for (int rr = 0; rr < 2; ++rr) {
            int k = kb + rr * 16;
            float4 v = *(const float4*)(W + (long)(k0 + k) * ldw + n0 + nq * 4);
            *(float4*)&Bs[k][nq * 4] = v;
        }
        __syncthreads();
        // ---- compute ----
        #pragma unroll
        for (int kk = 0; kk < KT; ++kk) {
            float a0 = As[ty*4+0][kk];
            float a1 = As[ty*4+1][kk];
            float a2 = As[ty*4+2][kk];
            float a3 = As[ty*4+3][kk];
            float4 bv = *(const float4*)&Bs[kk][tx * 4];
            acc[0][0] = fmaf(a0, bv.x, acc[0][0]);
            acc[0][1] = fmaf(a0, bv.y, acc[0][1]);
            acc[0][2] = fmaf(a0, bv.z, acc[0][2]);
            acc[0][3] = fmaf(a0, bv.w, acc[0][3]);
            acc[1][0] = fmaf(a1, bv.x, acc[1][0]);
            acc[1][1] = fmaf(a1, bv.y, acc[1][1]);
            acc[1][2] = fmaf(a1, bv.z, acc[1][2]);
            acc[1][3] = fmaf(a1, bv.w, acc[1][3]);
            acc[2][0] = fmaf(a2, bv.x, acc[2][0]);
            acc[2][1] = fmaf(a2, bv.y, acc[2][1]);
            acc[2][2] = fmaf(a2, bv.z, acc[2][2]);
            acc[2][3] = fmaf(a2, bv.w, acc[2][3]);
            acc[3][0] = fmaf(a3, bv.x, acc[3][0]);
            acc[3][1] = fmaf(a3, bv.y, acc[3][1]);
            acc[3][2] = fmaf(a3, bv.z, acc[3][2]);
            acc[3][3] = fmaf(a3, bv.w, acc[3][3]);
        }
        __syncthreads();
    }

    // ---- epilogue ----
    #pragma unroll
    for (int i = 0; i < 4; ++i) {
        int m = ty * 4 + i;
        int row = m0 + m;
        if (row >= Trows) continue;
        long coff = (rowbase + m) * (long)N + n0 + tx * 4;
        int n = n0 + tx * 4;
        float4 r;
        if (EPI == 0) {
            r.x = acc[i][0] + bias[n+0];
            r.y = acc[i][1] + bias[n+1];
            r.z = acc[i][2] + bias[n+2];
            r.w = acc[i][3] + bias[n+3];
        } else if (EPI == 1) {
            bool val = row < len;
            r.x = val ? fmaxf(acc[i][0] + bias[n+0], 0.f) : 0.f;
            r.y = val ? fmaxf(acc[i][1] + bias[n+1], 0.f) : 0.f;
            r.z = val ? fmaxf(acc[i][2] + bias[n+2], 0.f) : 0.f;
            r.w = val ? fmaxf(acc[i][3] + bias[n+3], 0.f) : 0.f;
        } else if (EPI == 2) {
            const float* rv = rowvec + b * 256;
            float v0 = fmaxf(acc[i][0] + rv[n+0], 0.f);
            float v1 = fmaxf(acc[i][1] + rv[n+1], 0.f);
            float v2 = fmaxf(acc[i][2] + rv[n+2], 0.f);
            float v3 = fmaxf(acc[i][3] + rv[n+3], 0.f);
            r.x = tanhf(v0 * g0[n+0] + g1[n+0]);
            r.y = tanhf(v1 * g0[n+1] + g1[n+1]);
            r.z = tanhf(v2 * g0[n+2] + g1[n+2]);
            r.w = tanhf(v3 * g0[n+3] + g1[n+3]);
        } else { // EPI 4
            float4 old = *(const float4*)(Aold + coff);
            const float* rv = rowvec + b * 256;
            r.x = old.x + tanhf(acc[i][0] + rv[n+0]);
            r.y = old.y + tanhf(acc[i][1] + rv[n+1]);
            r.z = old.z + tanhf(acc[i][2] + rv[n+2]);
            r.w = old.w + tanhf(acc[i][3] + rv[n+3]);
        }
        *(float4*)(C + coff) = r;
    }
}

// Per-sample GlobalLayerNorm stats over aux[b, :len, :] (contiguous len*256 floats)
__global__ __launch_bounds__(256) void gln_reduce_k(const float* __restrict__ aux,
    const int* __restrict__ lens, float* __restrict__ meanArr, float* __restrict__ rstdArr)
{
    int b = blockIdx.x, tid = threadIdx.x;
    int len = lens[b];
    long n = (long)len * 256;
    const float* p = aux + (long)b * 400 * 256;
    float s = 0.f, ss = 0.f;
    for (long i = tid; i < n; i += 256) { float v = p[i]; s += v; ss += v * v; }
    __shared__ float l1[4], l2[4];
    for (int off = 32; off; off >>= 1) { s += __shfl_down(s, off); ss += __shfl_down(ss, off); }
    if ((tid & 63) == 0) { l1[tid >> 6] = s; l2[tid >> 6] = ss; }
    __syncthreads();
    if (tid == 0) {
        s = l1[0] + l1[1] + l1[2] + l1[3];
        ss = l2[0] + l2[1] + l2[2] + l2[3];
        float cnt = (float)n;
        float mean = s / cnt;
        float var = ss / cnt - mean * mean;
        meanArr[b] = mean;
        rstdArr[b] = 1.0f / sqrtf(var + 1e-5f);
    }
}

// Per-(b,c) time stats of h + fused attbias[b,c] = att_b1 + m@W1m + s@W1s
__global__ __launch_bounds__(256) void stats_k(const float* __restrict__ h,
    const int* __restrict__ lens, const float* __restrict__ att_w1,
    const float* __restrict__ att_b1, float* __restrict__ attbias)
{
    int b = blockIdx.x, c = threadIdx.x;
    int len = lens[b];
    const float* p = h + (long)b * 400 * 256 + c;
    float s = 0.f, ss = 0.f;
    for (int t = 0; t < len; ++t) { float v = p[(long)t * 256]; s += v; ss += v * v; }
    float n = (float)len;
    float m = s / n;
    float var = (ss - n * m * m) / (n - 1.0f);
    float sd = sqrtf(fmaxf(var, 1e-4f));
    __shared__ float mS[256], sS[256];
    mS[c] = m; sS[c] = sd;
    __syncthreads();
    float acc = att_b1[c];
    for (int k = 0; k < 256; ++k) acc = fmaf(mS[k], att_w1[(256 + k) * 256 + c], acc);
    for (int k = 0; k < 256; ++k) acc = fmaf(sS[k], att_w1[(512 + k) * 256 + c], acc);
    attbias[b * 256 + c] = acc;
}

// Masked softmax over time + attentive pooling -> e5 = concat(mu,sg)*bn5_g+bn5_b
__global__ __launch_bounds__(256) void softmax_pool_k(const float* __restrict__ logits,
    const float* __restrict__ h, const int* __restrict__ lens,
    const float* __restrict__ bn5g, const float* __restrict__ bn5b, float* __restrict__ e5)
{
    int b = blockIdx.x, c = threadIdx.x;
    int len = lens[b];
    const float* lp = logits + (long)b * 400 * 256 + c;
    const float* hp = h + (long)b * 400 * 256 + c;
    float mx = -1e30f;
    for (int t = 0; t < len; ++t) mx = fmaxf(mx, lp[(long)t * 256]);
    float den = 0.f, mu = 0.f, m2 = 0.f;
    for (int t = 0; t < len; ++t) {
        float e = expf(lp[(long)t * 256] - mx);
        float hv = hp[(long)t * 256];
        den += e;
        mu = fmaf(e, hv, mu);
        m2 = fmaf(e * hv, hv, m2);
    }
    mu /= den; m2 /= den;
    float sg = sqrtf(fmaxf(m2 - mu * mu, 1e-4f));
    e5[b * 512 + c]       = mu * bn5g[c] + bn5b[c];
    e5[b * 512 + 256 + c] = sg * bn5g[256 + c] + bn5b[256 + c];
}

// fc6+bn6 -> emb ; L2-normalize -> classify -> d_out ; arnvec[i] = emb@arn_w2[i]+arn_b[i]
__global__ __launch_bounds__(256) void emb_k(const float* __restrict__ e5,
    const float* __restrict__ fc6w, const float* __restrict__ fc6b,
    const float* __restrict__ bn6g, const float* __restrict__ bn6b,
    const float* __restrict__ clsw, const float* __restrict__ clsb,
    const float* __restrict__ arnw2, const float* __restrict__ arnb,
    float* __restrict__ classify, float* __restrict__ arnvec)
{
    int b = blockIdx.x, c = threadIdx.x;
    __shared__ float es[512], embS[256], red[4];
    es[c] = e5[b * 512 + c];
    es[c + 256] = e5[b * 512 + 256 + c];
    __syncthreads();
    float acc = fc6b[c];
    for (int k = 0; k < 512; ++k) acc = fmaf(es[k], fc6w[k * 256 + c], acc);
    float emb = acc * bn6g[c] + bn6b[c];
    embS[c] = emb;
    __syncthreads();
    float sq = emb * emb;
    for (int off = 32; off; off >>= 1) sq += __shfl_down(sq, off);
    if ((c & 63) == 0) red[c >> 6] = sq;
    __syncthreads();
    float ss = red[0] + red[1] + red[2] + red[3];
    float inv = 1.0f / fmaxf(sqrtf(ss), 1e-12f);
    if (c < 101) {
        float o = clsb[c];
        for (int k = 0; k < 256; ++k) o = fmaf(embS[k] * inv, clsw[k * 101 + c], o);
        classify[b * 101 + c] = o;
    }
    for (int i = 0; i < 4; ++i) {
        float a = arnb[i * 256 + c];
        const float* w = arnw2 + (long)i * 256 * 256;
        for (int k = 0; k < 256; ++k) a = fmaf(embS[k], w[k * 256 + c], a);
        arnvec[(i * 32 + b) * 256 + c] = a;
    }
}

// Overlap-add: out[b,p] = (y[b,t0,p-160*t0] + (t0>0 ? y[b,t0-1,p-160*(t0-1)] : 0)) / den
__global__ __launch_bounds__(256) void ola_k(const float* __restrict__ y, float* __restrict__ out)
{
    int g = blockIdx.x * 256 + threadIdx.x;
    if (g >= 32 * 160000) return;
    int b = g / 160000;
    int p = g - b * 160000;
    int t0 = p / 160;
    int k0 = p - t0 * 160;
    const float* yb = y + (long)b * 1000 * 320;
    float v = yb[(long)t0 * 320 + k0];
    if (t0 > 0) { v += yb[(long)(t0 - 1) * 320 + k0 + 160]; v *= 0.5f; }
    out[g] = v;
}

extern "C" void kernel_launch(void* const* d_in, const int* in_sizes, int n_in,
                              void* d_out, int out_size, void* d_ws, size_t ws_size,
                              hipStream_t stream)
{
    (void)in_sizes; (void)n_in; (void)out_size; (void)ws_size;
    const float* input   = (const float*)d_in[0];
    const float* anchor  = (const float*)d_in[1];
    const int*   aux_len = (const int*)d_in[2];
    // d_in[3] = input_len: unused by the reference forward
    const float* in_w    = (const float*)d_in[4];
    const float* in_b    = (const float*)d_in[5];
    const float* out_w   = (const float*)d_in[6];
    const float* out_b   = (const float*)d_in[7];
    const float* gln_g   = (const float*)d_in[8];
    const float* gln_b   = (const float*)d_in[9];
    const float* ecapa_w = (const float*)d_in[10];
    const float* ecapa_b = (const float*)d_in[11];
    const float* att_w1  = (const float*)d_in[12];
    const float* att_b1  = (const float*)d_in[13];
    const float* attbn_g = (const float*)d_in[14];
    const float* attbn_b = (const float*)d_in[15];
    const float* att_w2  = (const float*)d_in[16];
    const float* att_b2  = (const float*)d_in[17];
    const float* bn5_g   = (const float*)d_in[18];
    const float* bn5_b   = (const float*)d_in[19];
    const float* fc6_w   = (const float*)d_in[20];
    const float* fc6_b   = (const float*)d_in[21];
    const float* bn6_g   = (const float*)d_in[22];
    const float* bn6_b   = (const float*)d_in[23];
    const float* cls_w   = (const float*)d_in[24];
    const float* cls_b   = (const float*)d_in[25];
    const float* arn_w1  = (const float*)d_in[26];
    const float* arn_w2  = (const float*)d_in[27];
    const float* arn_b   = (const float*)d_in[28];

    float* out_sig = (float*)d_out;
    float* out_cls = out_sig + (long)32 * 160000;

    float* ws = (float*)d_ws;
    // layout (floats): lifetimes allow y to overlap outB+aux
    float* out0   = ws;                    //  8,192,000  [B,1000,256]
    float* outB   = ws + 8192000;          //  8,192,000  ARN ping-pong
    float* aux    = ws + 16384000;         //  3,276,800  [B,400,256] (reused as logits)
    float* logits = aux;
    float* h      = ws + 19660800;         //  3,276,800
    float* a2     = ws + 22937600;         //  3,276,800
    float* y      = outB;                  // 10,240,000  [B,1000,320] (outB+aux dead by then)
    float* smallb = ws + 26214400;
    float* meanA   = smallb;               // 32
    float* rstdA   = smallb + 32;          // 32
    float* attbias = smallb + 64;          // 8192
    float* e5      = smallb + 64 + 8192;   // 16384
    float* arnvec  = e5 + 16384;           // 32768

    dim3 blk(256);

    // frames @ in_w + in_b  -> out0 [B,1000,256]
    gemm_k<1, 0><<<dim3(4, 16, 32), blk, 0, stream>>>(input, in_w, 256, in_b, out0,
        nullptr, nullptr, nullptr, nullptr, nullptr, nullptr, nullptr, 1000, 320, 256, 160000);
    // aux_frames @ in_w + in_b -> aux [B,400,256]
    gemm_k<1, 0><<<dim3(4, 7, 32), blk, 0, stream>>>(anchor, in_w, 256, in_b, aux,
        nullptr, nullptr, nullptr, nullptr, nullptr, nullptr, nullptr, 400, 320, 256, 64000);
    // GLN stats
    gln_reduce_k<<<32, blk, 0, stream>>>(aux, aux_len, meanA, rstdA);
    // h = relu(GLN(aux) @ ecapa_w + ecapa_b) * mask
    gemm_k<2, 1><<<dim3(4, 7, 32), blk, 0, stream>>>(aux, ecapa_w, 256, ecapa_b, h,
        nullptr, nullptr, gln_g, gln_b, meanA, rstdA, aux_len, 400, 256, 256, 0);
    // time stats + attbias
    stats_k<<<32, blk, 0, stream>>>(h, aux_len, att_w1, att_b1, attbias);
    // a2 = tanh(relu(h @ W1h + attbias) * attbn_g + attbn_b)
    gemm_k<0, 2><<<dim3(4, 7, 32), blk, 0, stream>>>(h, att_w1, 256, nullptr, a2,
        nullptr, attbias, attbn_g, attbn_b, nullptr, nullptr, nullptr, 400, 256, 256, 0);
    // logits = a2 @ att_w2 + att_b2
    gemm_k<0, 0><<<dim3(4, 7, 32), blk, 0, stream>>>(a2, att_w2, 256, att_b2, logits,
        nullptr, nullptr, nullptr, nullptr, nullptr, nullptr, nullptr, 400, 256, 256, 0);
    // softmax over valid time + pooling + bn5
    softmax_pool_k<<<32, blk, 0, stream>>>(logits, h, aux_len, bn5_g, bn5_b, e5);
    // emb pipeline: fc6+bn6, classify -> d_out, arnvec
    emb_k<<<32, blk, 0, stream>>>(e5, fc6_w, fc6_b, bn6_g, bn6_b, cls_w, cls_b,
                                  arn_w2, arn_b, out_cls, arnvec);
    // 4 ARN blocks, ping-pong out0 <-> outB (final result lands in out0)
    float* bufs[2] = { out0, outB };
    for (int i = 0; i < 4; ++i) {
        const float* src = bufs[i & 1];
        float* dst = bufs[(i + 1) & 1];
        gemm_k<0, 4><<<dim3(4, 16, 32), blk, 0, stream>>>(src, arn_w1 + (long)i * 65536, 256,
            nullptr, dst, src, arnvec + i * 8192,
            nullptr, nullptr, nullptr, nullptr, nullptr, 1000, 256, 256, 0);
    }
    // y = out0 @ out_w + out_b  [B,1000,320]
    gemm_k<0, 0><<<dim3(5, 16, 32), blk, 0, stream>>>(out0, out_w, 320, out_b, y,
        nullptr, nullptr, nullptr, nullptr, nullptr, nullptr, nullptr, 1000, 256, 320, 0);
    // overlap-add -> d_out signal
    ola_k<<<dim3(20000), blk, 0, stream>>>(y, out_sig);
}

// Round 2
// 544.400 us; speedup vs baseline: 2.0311x; 2.0311x over previous
//
#include <hip/hip_runtime.h>
#include <math.h>

typedef __attribute__((ext_vector_type(4))) float f32x4;
typedef __attribute__((ext_vector_type(8))) short short8;

__device__ __forceinline__ short f2bf(float f) {
    unsigned u = __builtin_bit_cast(unsigned, f);
    u += 0x7FFFu + ((u >> 16) & 1u);          // RNE (inputs are finite)
    return (short)(u >> 16);
}
__device__ __forceinline__ short8 pack8(const float* x) {
    short8 r;
    #pragma unroll
    for (int i = 0; i < 8; ++i) r[i] = f2bf(x[i]);
    return r;
}

// ---------------- weight transpose+convert: WT[n][k] bf16 <- W[k][n] f32 ----
// segments: in_wT [256][320] | ecapa_wT [256][256] | att_w1hT [256][256] |
//           att_w2T [256][256] | arn_w1T 4x[256][256] | out_wT [384][256] (pad)
__global__ __launch_bounds__(256) void convert_wt_k(
    const float* __restrict__ in_w, const float* __restrict__ ecapa_w,
    const float* __restrict__ att_w1, const float* __restrict__ att_w2,
    const float* __restrict__ arn_w1, const float* __restrict__ out_w,
    short* __restrict__ WT)
{
    int id = blockIdx.x * 256 + threadIdx.x;
    if (id < 81920) { int n = id / 320, k = id - n * 320; WT[id] = f2bf(in_w[k * 256 + n]); return; }
    id -= 81920;
    if (id < 65536) { int n = id >> 8, k = id & 255; WT[81920 + (n << 8) + k] = f2bf(ecapa_w[k * 256 + n]); return; }
    id -= 65536;
    if (id < 65536) { int n = id >> 8, k = id & 255; WT[147456 + (n << 8) + k] = f2bf(att_w1[k * 256 + n]); return; }
    id -= 65536;
    if (id < 65536) { int n = id >> 8, k = id & 255; WT[212992 + (n << 8) + k] = f2bf(att_w2[k * 256 + n]); return; }
    id -= 65536;
    if (id < 262144) {
        int i = id >> 16, r = id & 65535, n = r >> 8, k = r & 255;
        WT[278528 + id] = f2bf(arn_w1[i * 65536 + k * 256 + n]); return;
    }
    id -= 262144;
    if (id < 98304) {
        int n = id >> 8, k = id & 255;
        WT[540672 + id] = (n < 320) ? f2bf(out_w[k * 320 + n]) : (short)0; return;
    }
}

// ---------------- bf16 MFMA GEMM: C[row,n] = epi( sum_k A[row,k]*W[k,n] ) ----
// 128x128 tile, BK=32, 256 thr = 4 waves (2x2 of 64x64), 16x16x32 bf16 MFMA.
// AMODE 0: dense f32 [M,K] | 1: framed signal | 2: GLN-normalized aux (masked)
// EPI 0: +bias | 1: masked relu(+bias) | 2: tanh(relu(acc+rowvec)*ng0+ng1)
// EPI 4: Aold + tanh(acc + rowvec)
template<int AMODE, int EPI, int TPB>
__global__ __launch_bounds__(256) void mfma_gemm_k(
    const float* __restrict__ Asrc, const short* __restrict__ WT,
    const float* __restrict__ bias, float* __restrict__ C,
    const float* __restrict__ Aold, const float* __restrict__ rowvec,
    const float* __restrict__ ng0, const float* __restrict__ ng1,
    const float* __restrict__ kg0, const float* __restrict__ kg1,
    const float* __restrict__ stat0, const float* __restrict__ stat1,
    const int* __restrict__ lens,
    int K, int N, int Lsig)
{
    __shared__ short As[128 * 32];
    __shared__ short Bs[128 * 32];
    const int tid = threadIdx.x;
    const int n0 = blockIdx.x * 128, m0 = blockIdx.y * 128;
    const int rl = tid >> 1, kh = tid & 1;          // staging: row, k-half
    const int lane = tid & 63, w = tid >> 6;
    const int wm = w >> 1, wn = w & 1;
    const int lr = lane & 15, ls = lane >> 4;

    const int arow = m0 + rl;
    const float* aptr;
    int tt = 0, alen = 0;
    float mean = 0.f, rstd = 0.f;
    if (AMODE == 0) {
        aptr = Asrc + (long)arow * K;
    } else {
        int b = arow / TPB; tt = arow - b * TPB;
        if (AMODE == 1) aptr = Asrc + (long)b * Lsig + 160 * tt;
        else { aptr = Asrc + (long)arow * 256; alen = lens[b]; mean = stat0[b]; rstd = stat1[b]; }
    }
    const short* bsrc = WT + (long)(n0 + rl) * K;

    const int s0 = (2 * kh) ^ (rl & 3), s1 = (2 * kh + 1) ^ (rl & 3);
    short* aw0 = &As[rl * 32 + s0 * 8]; short* aw1 = &As[rl * 32 + s1 * 8];
    short* bw0 = &Bs[rl * 32 + s0 * 8]; short* bw1 = &Bs[rl * 32 + s1 * 8];
    const int rco = (ls ^ (lr & 3)) * 8;            // swizzled frag k-slot

    f32x4 acc[4][4] = {};

    for (int k0 = 0; k0 < K; k0 += 32) {
        const int kk = k0 + kh * 16;
        float x[16];
        if (AMODE == 0) {
            const float4* p = (const float4*)(aptr + kk);
            #pragma unroll
            for (int i = 0; i < 4; ++i) {
                float4 v = p[i];
                x[i*4+0]=v.x; x[i*4+1]=v.y; x[i*4+2]=v.z; x[i*4+3]=v.w;
            }
        } else if (AMODE == 1) {
            int base = 160 * tt + kk;
            if (base + 15 < Lsig) {
                const float4* p = (const float4*)(aptr + kk);
                #pragma unroll
                for (int i = 0; i < 4; ++i) {
                    float4 v = p[i];
                    x[i*4+0]=v.x; x[i*4+1]=v.y; x[i*4+2]=v.z; x[i*4+3]=v.w;
                }
            } else {
                #pragma unroll
                for (int e = 0; e < 16; ++e) x[e] = (base + e < Lsig) ? aptr[kk + e] : 0.f;
            }
        } else {
            if (tt < alen) {
                const float4* p = (const float4*)(aptr + kk);
                const float4* gg = (const float4*)(kg0 + kk);
                const float4* gb = (const float4*)(kg1 + kk);
                #pragma unroll
                for (int i = 0; i < 4; ++i) {
                    float4 v = p[i], g = gg[i], hb = gb[i];
                    x[i*4+0] = g.x * (v.x - mean) * rstd + hb.x;
                    x[i*4+1] = g.y * (v.y - mean) * rstd + hb.y;
                    x[i*4+2] = g.z * (v.z - mean) * rstd + hb.z;
                    x[i*4+3] = g.w * (v.w - mean) * rstd + hb.w;
                }
            } else {
                #pragma unroll
                for (int e = 0; e < 16; ++e) x[e] = 0.f;
            }
        }
        short8 alo = pack8(x), ahi = pack8(x + 8);
        short8 blo = *(const short8*)(bsrc + kk);
        short8 bhi = *(const short8*)(bsrc + kk + 8);
        *(short8*)aw0 = alo; *(short8*)aw1 = ahi;
        *(short8*)bw0 = blo; *(short8*)bw1 = bhi;
        __syncthreads();
        short8 af[4], bfr[4];
        #pragma unroll
        for (int f = 0; f < 4; ++f) {
            af[f]  = *(const short8*)&As[(wm * 64 + f * 16 + lr) * 32 + rco];
            bfr[f] = *(const short8*)&Bs[(wn * 64 + f * 16 + lr) * 32 + rco];
        }
        #pragma unroll
        for (int fr = 0; fr < 4; ++fr)
            #pragma unroll
            for (int fc = 0; fc < 4; ++fc)
                acc[fr][fc] = __builtin_amdgcn_mfma_f32_16x16x32_bf16(af[fr], bfr[fc], acc[fr][fc], 0, 0, 0);
        __syncthreads();
    }

    #pragma unroll
    for (int fr = 0; fr < 4; ++fr) {
        #pragma unroll
        for (int j = 0; j < 4; ++j) {
            const int row = m0 + wm * 64 + fr * 16 + ls * 4 + j;
            int bb = 0, tloc = 0;
            if (EPI != 0) { bb = row / TPB; tloc = row - bb * TPB; }
            const float* rv = (EPI >= 2) ? rowvec + bb * 256 : nullptr;
            const int lenb = (EPI == 1) ? lens[bb] : 0;
            (void)tloc;
            #pragma unroll
            for (int fc = 0; fc < 4; ++fc) {
                const int col = n0 + wn * 64 + fc * 16 + lr;
                if (col >= N) continue;
                float v = acc[fr][fc][j];
                float r;
                if (EPI == 0) r = v + bias[col];
                else if (EPI == 1) r = (tloc < lenb) ? fmaxf(v + bias[col], 0.f) : 0.f;
                else if (EPI == 2) {
                    float u = fmaxf(v + rv[col], 0.f);
                    r = tanhf(u * ng0[col] + ng1[col]);
                } else {
                    r = Aold[(long)row * 256 + col] + tanhf(v + rv[col]);
                }
                C[(long)row * N + col] = r;
            }
        }
    }
}

// ---------------- per-sample GLN stats (1024 thr, float4) ----------------
__global__ __launch_bounds__(1024) void gln_reduce_k(const float* __restrict__ aux,
    const int* __restrict__ lens, float* __restrict__ meanArr, float* __restrict__ rstdArr)
{
    int b = blockIdx.x, tid = threadIdx.x;
    int len = lens[b];
    int n4 = len * 64;
    const float4* p = (const float4*)(aux + (long)b * 400 * 256);
    float s = 0.f, ss = 0.f;
    for (int i = tid; i < n4; i += 1024) {
        float4 v = p[i];
        s += v.x + v.y + v.z + v.w;
        ss += v.x*v.x + v.y*v.y + v.z*v.z + v.w*v.w;
    }
    for (int off = 32; off; off >>= 1) { s += __shfl_down(s, off); ss += __shfl_down(ss, off); }
    __shared__ float l1[16], l2[16];
    if ((tid & 63) == 0) { l1[tid >> 6] = s; l2[tid >> 6] = ss; }
    __syncthreads();
    if (tid == 0) {
        s = 0.f; ss = 0.f;
        for (int i = 0; i < 16; ++i) { s += l1[i]; ss += l2[i]; }
        float cnt = (float)len * 256.f;
        float mean = s / cnt;
        float var = ss / cnt - mean * mean;
        meanArr[b] = mean;
        rstdArr[b] = 1.0f / sqrtf(var + 1e-5f);
    }
}

// -------- per-(b,c) time stats + attbias = att_b1 + m@W1m + s@W1s --------
__global__ __launch_bounds__(1024) void stats_k(const float* __restrict__ h,
    const int* __restrict__ lens, const float* __restrict__ att_w1,
    const float* __restrict__ att_b1, float* __restrict__ attbias)
{
    int b = blockIdx.x, tid = threadIdx.x;
    int g = tid >> 8, c = tid & 255;
    int len = lens[b];
    const float* p = h + (long)b * 400 * 256 + c;
    float s = 0.f, ss = 0.f;
    for (int t = g; t < len; t += 4) { float v = p[(long)t * 256]; s += v; ss += v * v; }
    __shared__ float sP[4][256], ssP[4][256];
    __shared__ float mS[256], sS[256];
    sP[g][c] = s; ssP[g][c] = ss;
    __syncthreads();
    if (g == 0) {
        s  = sP[0][c] + sP[1][c] + sP[2][c] + sP[3][c];
        ss = ssP[0][c] + ssP[1][c] + ssP[2][c] + ssP[3][c];
        float n = (float)len;
        float m = s / n;
        float var = (ss - n * m * m) / (n - 1.0f);
        mS[c] = m; sS[c] = sqrtf(fmaxf(var, 1e-4f));
    }
    __syncthreads();
    float acc = 0.f;
    for (int k = g * 64; k < g * 64 + 64; ++k) {
        acc = fmaf(mS[k], att_w1[(256 + k) * 256 + c], acc);
        acc = fmaf(sS[k], att_w1[(512 + k) * 256 + c], acc);
    }
    sP[g][c] = acc;
    __syncthreads();
    if (g == 0) attbias[b * 256 + c] = att_b1[c] + sP[0][c] + sP[1][c] + sP[2][c] + sP[3][c];
}

// -------- masked softmax over time + attentive pooling + bn5 --------
__global__ __launch_bounds__(1024) void softmax_pool_k(const float* __restrict__ logits,
    const float* __restrict__ h, const int* __restrict__ lens,
    const float* __restrict__ bn5g, const float* __restrict__ bn5b, float* __restrict__ e5)
{
    int b = blockIdx.x, tid = threadIdx.x;
    int g = tid >> 8, c = tid & 255;
    int len = lens[b];
    const float* lp = logits + (long)b * 400 * 256 + c;
    const float* hp = h + (long)b * 400 * 256 + c;
    __shared__ float mP[4][256], dP[4][256], muP[4][256], m2P[4][256];
    __shared__ float mxS[256];
    float mx = -1e30f;
    for (int t = g; t < len; t += 4) mx = fmaxf(mx, lp[(long)t * 256]);
    mP[g][c] = mx;
    __syncthreads();
    if (g == 0) mxS[c] = fmaxf(fmaxf(mP[0][c], mP[1][c]), fmaxf(mP[2][c], mP[3][c]));
    __syncthreads();
    float M = mxS[c], den = 0.f, mu = 0.f, m2 = 0.f;
    for (int t = g; t < len; t += 4) {
        float e = expf(lp[(long)t * 256] - M);
        float hv = hp[(long)t * 256];
        den += e;
        mu = fmaf(e, hv, mu);
        m2 = fmaf(e * hv, hv, m2);
    }
    dP[g][c] = den; muP[g][c] = mu; m2P[g][c] = m2;
    __syncthreads();
    if (g == 0) {
        den = dP[0][c] + dP[1][c] + dP[2][c] + dP[3][c];
        mu  = (muP[0][c] + muP[1][c] + muP[2][c] + muP[3][c]) / den;
        m2  = (m2P[0][c] + m2P[1][c] + m2P[2][c] + m2P[3][c]) / den;
        float sg = sqrtf(fmaxf(m2 - mu * mu, 1e-4f));
        e5[b * 512 + c]       = mu * bn5g[c] + bn5b[c];
        e5[b * 512 + 256 + c] = sg * bn5g[256 + c] + bn5b[256 + c];
    }
}

// -------- fc6+bn6 -> emb ; L2-norm -> classify ; arnvec[i]=emb@arn_w2[i]+b --
__global__ __launch_bounds__(1024) void emb_k(const float* __restrict__ e5,
    const float* __restrict__ fc6w, const float* __restrict__ fc6b,
    const float* __restrict__ bn6g, const float* __restrict__ bn6b,
    const float* __restrict__ clsw, const float* __restrict__ clsb,
    const float* __restrict__ arnw2, const float* __restrict__ arnb,
    float* __restrict__ classify, float* __restrict__ arnvec)
{
    int b = blockIdx.x, tid = threadIdx.x;
    int g = tid >> 8, c = tid & 255;
    __shared__ float es[512], embS[256], fP[4][256], red[4], cP[8][128];
    __shared__ float invS;
    if (tid < 512) es[tid] = e5[b * 512 + tid];
    __syncthreads();
    float acc = 0.f;
    for (int k = g * 128; k < g * 128 + 128; ++k)
        acc = fmaf(es[k], fc6w[k * 256 + c], acc);
    fP[g][c] = acc;
    __syncthreads();
    if (g == 0) {
        float e = fP[0][c] + fP[1][c] + fP[2][c] + fP[3][c] + fc6b[c];
        embS[c] = e * bn6g[c] + bn6b[c];
    }
    __syncthreads();
    if (tid < 256) {
        float sq = embS[tid] * embS[tid];
        for (int off = 32; off; off >>= 1) sq += __shfl_down(sq, off);
        if ((tid & 63) == 0) red[tid >> 6] = sq;
    }
    __syncthreads();
    if (tid == 0) invS = 1.0f / fmaxf(sqrtf(red[0] + red[1] + red[2] + red[3]), 1e-12f);
    __syncthreads();
    int g8 = tid >> 7, c7 = tid & 127;
    float a = 0.f;
    if (c7 < 101)
        for (int k = g8 * 32; k < g8 * 32 + 32; ++k)
            a = fmaf(embS[k], clsw[k * 101 + c7], a);
    cP[g8][c7] = a;
    __syncthreads();
    if (g8 == 0 && c7 < 101) {
        float ssum = 0.f;
        for (int q = 0; q < 8; ++q) ssum += cP[q][c7];
        classify[b * 101 + c7] = ssum * invS + clsb[c7];
    }
    float av = arnb[g * 256 + c];
    const float* wp = arnw2 + (long)g * 65536;
    for (int k = 0; k < 256; ++k) av = fmaf(embS[k], wp[k * 256 + c], av);
    arnvec[(g * 32 + b) * 256 + c] = av;
}

// ---------------- overlap-add ----------------
__global__ __launch_bounds__(256) void ola_k(const float* __restrict__ y, float* __restrict__ out)
{
    int gidx = blockIdx.x * 256 + threadIdx.x;
    if (gidx >= 32 * 160000) return;
    int b = gidx / 160000;
    int p = gidx - b * 160000;
    int t0 = p / 160;
    int k0 = p - t0 * 160;
    const float* yb = y + (long)b * 1000 * 320;
    float v = yb[(long)t0 * 320 + k0];
    if (t0 > 0) { v += yb[(long)(t0 - 1) * 320 + k0 + 160]; v *= 0.5f; }
    out[gidx] = v;
}

extern "C" void kernel_launch(void* const* d_in, const int* in_sizes, int n_in,
                              void* d_out, int out_size, void* d_ws, size_t ws_size,
                              hipStream_t stream)
{
    (void)in_sizes; (void)n_in; (void)out_size; (void)ws_size;
    const float* input   = (const float*)d_in[0];
    const float* anchor  = (const float*)d_in[1];
    const int*   aux_len = (const int*)d_in[2];
    const float* in_w    = (const float*)d_in[4];
    const float* in_b    = (const float*)d_in[5];
    const float* out_w   = (const float*)d_in[6];
    const float* out_b   = (const float*)d_in[7];
    const float* gln_g   = (const float*)d_in[8];
    const float* gln_b   = (const float*)d_in[9];
    const float* ecapa_w = (const float*)d_in[10];
    const float* ecapa_b = (const float*)d_in[11];
    const float* att_w1  = (const float*)d_in[12];
    const float* att_b1  = (const float*)d_in[13];
    const float* attbn_g = (const float*)d_in[14];
    const float* attbn_b = (const float*)d_in[15];
    const float* att_w2  = (const float*)d_in[16];
    const float* att_b2  = (const float*)d_in[17];
    const float* bn5_g   = (const float*)d_in[18];
    const float* bn5_b   = (const float*)d_in[19];
    const float* fc6_w   = (const float*)d_in[20];
    const float* fc6_b   = (const float*)d_in[21];
    const float* bn6_g   = (const float*)d_in[22];
    const float* bn6_b   = (const float*)d_in[23];
    const float* cls_w   = (const float*)d_in[24];
    const float* cls_b   = (const float*)d_in[25];
    const float* arn_w1  = (const float*)d_in[26];
    const float* arn_w2  = (const float*)d_in[27];
    const float* arn_b   = (const float*)d_in[28];

    float* out_sig = (float*)d_out;
    float* out_cls = out_sig + (long)32 * 160000;

    float* ws = (float*)d_ws;
    float* o0     = ws;                    // [32000,256]
    float* oB     = ws + 8192000;          // ARN ping-pong / later y
    float* aux    = ws + 16384000;         // [12800,256], reused as logits
    float* logits = aux;
    float* h      = ws + 19660800;         // [12800,256]
    float* a2     = ws + 22937600;         // [12800,256]
    short* WT     = (short*)(ws + 26214400);  // 638976 bf16
    float* smalls = ws + 26533888;
    float* meanA   = smalls;
    float* rstdA   = smalls + 32;
    float* attbias = smalls + 64;
    float* e5      = smalls + 64 + 8192;
    float* arnvec  = e5 + 16384;
    float* y       = oB;                   // [32000,320] (oB+logits dead)

    short* WT_in  = WT;            // [256][320]
    short* WT_ec  = WT + 81920;    // [256][256]
    short* WT_a1  = WT + 147456;
    short* WT_a2  = WT + 212992;
    short* WT_arn = WT + 278528;   // 4x[256][256]
    short* WT_out = WT + 540672;   // [384][256] padded

    dim3 blk(256);

    convert_wt_k<<<dim3(2496), blk, 0, stream>>>(in_w, ecapa_w, att_w1, att_w2, arn_w1, out_w, WT);

    // frames @ in_w + in_b -> o0
    mfma_gemm_k<1, 0, 1000><<<dim3(2, 250), blk, 0, stream>>>(input, WT_in, in_b, o0,
        nullptr, nullptr, nullptr, nullptr, nullptr, nullptr, nullptr, nullptr, nullptr,
        320, 256, 160000);
    // aux frames @ in_w + in_b -> aux
    mfma_gemm_k<1, 0, 400><<<dim3(2, 100), blk, 0, stream>>>(anchor, WT_in, in_b, aux,
        nullptr, nullptr, nullptr, nullptr, nullptr, nullptr, nullptr, nullptr, nullptr,
        320, 256, 64000);
    gln_reduce_k<<<dim3(32), dim3(1024), 0, stream>>>(aux, aux_len, meanA, rstdA);
    // h = relu(GLN(aux) @ ecapa_w + b) * mask
    mfma_gemm_k<2, 1, 400><<<dim3(2, 100), blk, 0, stream>>>(aux, WT_ec, ecapa_b, h,
        nullptr, nullptr, nullptr, nullptr, gln_g, gln_b, meanA, rstdA, aux_len,
        256, 256, 0);
    stats_k<<<dim3(32), dim3(1024), 0, stream>>>(h, aux_len, att_w1, att_b1, attbias);
    // a2 = tanh(relu(h @ W1h + attbias) * attbn_g + attbn_b)
    mfma_gemm_k<0, 2, 400><<<dim3(2, 100), blk, 0, stream>>>(h, WT_a1, nullptr, a2,
        nullptr, attbias, attbn_g, attbn_b, nullptr, nullptr, nullptr, nullptr, nullptr,
        256, 256, 0);
    // logits = a2 @ att_w2 + att_b2
    mfma_gemm_k<0, 0, 400><<<dim3(2, 100), blk, 0, stream>>>(a2, WT_a2, att_b2, logits,
        nullptr, nullptr, nullptr, nullptr, nullptr, nullptr, nullptr, nullptr, nullptr,
        256, 256, 0);
    softmax_pool_k<<<dim3(32), dim3(1024), 0, stream>>>(logits, h, aux_len, bn5_g, bn5_b, e5);
    emb_k<<<dim3(32), dim3(1024), 0, stream>>>(e5, fc6_w, fc6_b, bn6_g, bn6_b, cls_w, cls_b,
                                               arn_w2, arn_b, out_cls, arnvec);
    // 4 ARN blocks, ping-pong (final in o0)
    float* bufs[2] = { o0, oB };
    for (int i = 0; i < 4; ++i) {
        const float* src = bufs[i & 1];
        float* dst = bufs[(i + 1) & 1];
        mfma_gemm_k<0, 4, 1000><<<dim3(2, 250), blk, 0, stream>>>(src, WT_arn + i * 65536,
            nullptr, dst, src, arnvec + i * 8192,
            nullptr, nullptr, nullptr, nullptr, nullptr, nullptr, nullptr,
            256, 256, 0);
    }
    // y = o0 @ out_w + out_b  [32000,320]
    mfma_gemm_k<0, 0, 1000><<<dim3(3, 250), blk, 0, stream>>>(o0, WT_out, out_b, y,
        nullptr, nullptr, nullptr, nullptr, nullptr, nullptr, nullptr, nullptr, nullptr,
        256, 320, 0);
    ola_k<<<dim3(20000), blk, 0, stream>>>(y, out_sig);
}

// Round 3
// 510.816 us; speedup vs baseline: 2.1646x; 1.0657x over previous
//
#include <hip/hip_runtime.h>
#include <math.h>

typedef __attribute__((ext_vector_type(4))) float f32x4;
typedef __attribute__((ext_vector_type(8))) short short8;

__device__ __forceinline__ short f2bf(float f) {
    unsigned u = __builtin_bit_cast(unsigned, f);
    u += 0x7FFFu + ((u >> 16) & 1u);          // RNE (inputs are finite)
    return (short)(u >> 16);
}
__device__ __forceinline__ short8 pack8(const float* x) {
    short8 r;
    #pragma unroll
    for (int i = 0; i < 8; ++i) r[i] = f2bf(x[i]);
    return r;
}
__device__ __forceinline__ void load16(const float* p, float* x) {
    const float4* q = (const float4*)p;
    #pragma unroll
    for (int i = 0; i < 4; ++i) {
        float4 v = q[i];
        x[i*4+0] = v.x; x[i*4+1] = v.y; x[i*4+2] = v.z; x[i*4+3] = v.w;
    }
}

// ---------------- weight transpose+convert: WT[n][k] bf16 <- W[k][n] f32 ----
// in_wT [256][320] | ecapa_wT' (g-scaled) [256][256] | att_w1hT [256][256] |
// att_w2T [256][256] | arn_w1T 4x[256][256] | out_wT [384][256] (pad)
__global__ __launch_bounds__(256) void convert_wt_k(
    const float* __restrict__ in_w, const float* __restrict__ ecapa_w,
    const float* __restrict__ att_w1, const float* __restrict__ att_w2,
    const float* __restrict__ arn_w1, const float* __restrict__ out_w,
    const float* __restrict__ gln_g, short* __restrict__ WT)
{
    int id = blockIdx.x * 256 + threadIdx.x;
    if (id < 81920) { int n = id / 320, k = id - n * 320; WT[id] = f2bf(in_w[k * 256 + n]); return; }
    id -= 81920;
    if (id < 65536) { int n = id >> 8, k = id & 255; WT[81920 + (n << 8) + k] = f2bf(gln_g[k] * ecapa_w[k * 256 + n]); return; }
    id -= 65536;
    if (id < 65536) { int n = id >> 8, k = id & 255; WT[147456 + (n << 8) + k] = f2bf(att_w1[k * 256 + n]); return; }
    id -= 65536;
    if (id < 65536) { int n = id >> 8, k = id & 255; WT[212992 + (n << 8) + k] = f2bf(att_w2[k * 256 + n]); return; }
    id -= 65536;
    if (id < 262144) {
        int i = id >> 16, r = id & 65535, n = r >> 8, k = r & 255;
        WT[278528 + id] = f2bf(arn_w1[i * 65536 + k * 256 + n]); return;
    }
    id -= 262144;
    if (id < 98304) {
        int n = id >> 8, k = id & 255;
        WT[540672 + id] = (n < 320) ? f2bf(out_w[k * 320 + n]) : (short)0; return;
    }
}

// u[n] = sum_k g[k] W[k][n] ; v[n] = sum_k gb[k] W[k][n] + ecapa_b[n]
__global__ __launch_bounds__(256) void glnuv_k(const float* __restrict__ ecapa_w,
    const float* __restrict__ gln_g, const float* __restrict__ gln_b,
    const float* __restrict__ ecapa_b, float* __restrict__ uArr, float* __restrict__ vArr)
{
    int n = threadIdx.x;
    float u = 0.f, v = 0.f;
    #pragma unroll 8
    for (int k = 0; k < 256; ++k) {
        float w = ecapa_w[k * 256 + n];
        u = fmaf(gln_g[k], w, u);
        v = fmaf(gln_b[k], w, v);
    }
    uArr[n] = u;
    vArr[n] = v + ecapa_b[n];
}

// ---------------- bf16 MFMA GEMM: C[row,n] = epi( sum_k A[row,k]*W[k,n] ) ----
// 128x128 tile, BK=32, 256 thr = 4 waves (2x2 of 64x64), 16x16x32 bf16 MFMA,
// register-prefetch pipeline (loads for k+1 issue before the MFMA phase of k).
// AMODE 0: dense f32 [M,K] | 1: framed signal
// EPI 0: +bias | 2: tanh(relu(acc+rowvec)*ng0+ng1) | 4: Aold+tanh(acc+rowvec)
// EPI 5: masked GLN: (t<len) ? relu(rstd*(acc - mean*ng0[n]) + ng1[n]) : 0
template<int AMODE, int EPI, int TPB>
__global__ __launch_bounds__(256) void mfma_gemm_k(
    const float* __restrict__ Asrc, const short* __restrict__ WT,
    const float* __restrict__ bias, float* __restrict__ C,
    const float* __restrict__ Aold, const float* __restrict__ rowvec,
    const float* __restrict__ ng0, const float* __restrict__ ng1,
    const float* __restrict__ stat0, const float* __restrict__ stat1,
    const int* __restrict__ lens,
    int K, int N, int Lsig)
{
    __shared__ short As[128 * 32];
    __shared__ short Bs[128 * 32];
    const int tid = threadIdx.x;
    const int n0 = blockIdx.x * 128, m0 = blockIdx.y * 128;
    const int rl = tid >> 1, kh = tid & 1;          // staging: row, k-half
    const int lane = tid & 63, w = tid >> 6;
    const int wm = w >> 1, wn = w & 1;
    const int lr = lane & 15, ls = lane >> 4;

    const int arow = m0 + rl;
    const float* aptr;
    int tt = 0;
    if (AMODE == 0) {
        aptr = Asrc + (long)arow * K;
    } else {
        int b = arow / TPB; tt = arow - b * TPB;
        aptr = Asrc + (long)b * Lsig + 160 * tt;
    }
    const short* bsrc = WT + (long)(n0 + rl) * K;

    const int s0 = (2 * kh) ^ (rl & 3), s1 = (2 * kh + 1) ^ (rl & 3);
    short* aw0 = &As[rl * 32 + s0 * 8]; short* aw1 = &As[rl * 32 + s1 * 8];
    short* bw0 = &Bs[rl * 32 + s0 * 8]; short* bw1 = &Bs[rl * 32 + s1 * 8];
    const int rco = (ls ^ (lr & 3)) * 8;            // swizzled frag k-slot

    f32x4 acc[4][4] = {};
    float x[16];
    short8 blo, bhi;

    // prologue load (k0 = 0)
    {
        const int kk = kh * 16;
        if (AMODE == 0) {
            load16(aptr + kk, x);
        } else {
            int base = 160 * tt + kk;
            if (base + 15 < Lsig) load16(aptr + kk, x);
            else {
                #pragma unroll
                for (int e = 0; e < 16; ++e) x[e] = (base + e < Lsig) ? aptr[kk + e] : 0.f;
            }
        }
        blo = *(const short8*)(bsrc + kk);
        bhi = *(const short8*)(bsrc + kk + 8);
    }

    for (int k0 = 0; k0 < K; k0 += 32) {
        // pack & write current step's registers to LDS
        *(short8*)aw0 = pack8(x);
        *(short8*)aw1 = pack8(x + 8);
        *(short8*)bw0 = blo;
        *(short8*)bw1 = bhi;
        __syncthreads();
        // prefetch next step into registers (hides HBM under MFMA below)
        if (k0 + 32 < K) {
            const int kk = k0 + 32 + kh * 16;
            if (AMODE == 0) {
                load16(aptr + kk, x);
            } else {
                int base = 160 * tt + kk;
                if (base + 15 < Lsig) load16(aptr + kk, x);
                else {
                    #pragma unroll
                    for (int e = 0; e < 16; ++e) x[e] = (base + e < Lsig) ? aptr[kk + e] : 0.f;
                }
            }
            blo = *(const short8*)(bsrc + kk);
            bhi = *(const short8*)(bsrc + kk + 8);
        }
        short8 af[4], bfr[4];
        #pragma unroll
        for (int f = 0; f < 4; ++f) {
            af[f]  = *(const short8*)&As[(wm * 64 + f * 16 + lr) * 32 + rco];
            bfr[f] = *(const short8*)&Bs[(wn * 64 + f * 16 + lr) * 32 + rco];
        }
        #pragma unroll
        for (int fr = 0; fr < 4; ++fr)
            #pragma unroll
            for (int fc = 0; fc < 4; ++fc)
                acc[fr][fc] = __builtin_amdgcn_mfma_f32_16x16x32_bf16(af[fr], bfr[fc], acc[fr][fc], 0, 0, 0);
        __syncthreads();
    }

    #pragma unroll
    for (int fr = 0; fr < 4; ++fr) {
        #pragma unroll
        for (int j = 0; j < 4; ++j) {
            const int row = m0 + wm * 64 + fr * 16 + ls * 4 + j;
            int bb = 0, tloc = 0;
            if (EPI != 0) { bb = row / TPB; tloc = row - bb * TPB; }
            const float* rv = (EPI == 2 || EPI == 4) ? rowvec + bb * 256 : nullptr;
            float mean = 0.f, rstd = 0.f; int lenb = 0;
            if (EPI == 5) { mean = stat0[bb]; rstd = stat1[bb]; lenb = lens[bb]; }
            #pragma unroll
            for (int fc = 0; fc < 4; ++fc) {
                const int col = n0 + wn * 64 + fc * 16 + lr;
                if (col >= N) continue;
                float v = acc[fr][fc][j];
                float r;
                if (EPI == 0) r = v + bias[col];
                else if (EPI == 2) {
                    float u = fmaxf(v + rv[col], 0.f);
                    r = tanhf(u * ng0[col] + ng1[col]);
                } else if (EPI == 4) {
                    r = Aold[(long)row * 256 + col] + tanhf(v + rv[col]);
                } else { // EPI 5
                    r = (tloc < lenb) ? fmaxf(rstd * (v - mean * ng0[col]) + ng1[col], 0.f) : 0.f;
                }
                C[(long)row * N + col] = r;
            }
        }
    }
}

// ------------- GLN stats, phase 1: per-(b, chunk of 25 rows) partials -------
__global__ __launch_bounds__(256) void gln_part_k(const float* __restrict__ aux,
    const int* __restrict__ lens, float* __restrict__ part)
{
    int b = blockIdx.x, p = blockIdx.y, tid = threadIdx.x;
    int len = lens[b];
    int t0 = p * 25, t1 = min(len, t0 + 25);
    const float4* src = (const float4*)(aux + (long)b * 400 * 256);
    float s = 0.f, ss = 0.f;
    for (int i = t0 * 64 + tid; i < t1 * 64; i += 256) {
        float4 v = src[i];
        s += v.x + v.y + v.z + v.w;
        ss += v.x*v.x + v.y*v.y + v.z*v.z + v.w*v.w;
    }
    for (int off = 32; off; off >>= 1) { s += __shfl_down(s, off); ss += __shfl_down(ss, off); }
    __shared__ float l1[4], l2[4];
    if ((tid & 63) == 0) { l1[tid >> 6] = s; l2[tid >> 6] = ss; }
    __syncthreads();
    if (tid == 0) {
        part[b * 16 + p]       = l1[0] + l1[1] + l1[2] + l1[3];
        part[512 + b * 16 + p] = l2[0] + l2[1] + l2[2] + l2[3];
    }
}

// ------------- GLN stats, phase 2: combine 16 partials per sample -------
__global__ __launch_bounds__(512) void gln_comb_k(const float* __restrict__ part,
    const int* __restrict__ lens, float* __restrict__ meanA, float* __restrict__ rstdA)
{
    __shared__ float s1[32][16], s2[32][16];
    int tid = threadIdx.x, b = tid >> 4, p = tid & 15;
    s1[b][p] = part[b * 16 + p];
    s2[b][p] = part[512 + b * 16 + p];
    __syncthreads();
    if (tid < 32) {
        float s = 0.f, ss = 0.f;
        for (int q = 0; q < 16; ++q) { s += s1[tid][q]; ss += s2[tid][q]; }
        float cnt = (float)lens[tid] * 256.f;
        float mean = s / cnt;
        float var = ss / cnt - mean * mean;
        meanA[tid] = mean;
        rstdA[tid] = 1.0f / sqrtf(var + 1e-5f);
    }
}

// ------------- time stats, phase 1: per-(b, chunk of 50) s/ss per channel ---
__global__ __launch_bounds__(256) void stats_part_k(const float* __restrict__ h,
    const int* __restrict__ lens, float* __restrict__ part)
{
    int b = blockIdx.x, p = blockIdx.y, c = threadIdx.x;
    int len = lens[b];
    int t0 = p * 50, t1 = min(len, t0 + 50);
    const float* hp = h + ((long)b * 400 + t0) * 256 + c;
    float s = 0.f, ss = 0.f;
    for (int t = 0; t < t1 - t0; ++t) { float v = hp[(long)t * 256]; s += v; ss = fmaf(v, v, ss); }
    part[((long)b * 8 + p) * 256 + c] = s;
    part[65536 + ((long)b * 8 + p) * 256 + c] = ss;
}

// ------------- time stats, phase 2: combine + attbias matvec -------
__global__ __launch_bounds__(256) void stats_comb_k(const float* __restrict__ part,
    const int* __restrict__ lens, const float* __restrict__ att_w1,
    const float* __restrict__ att_b1, float* __restrict__ attbias)
{
    int b = blockIdx.x, c = threadIdx.x;
    float s = 0.f, ss = 0.f;
    #pragma unroll
    for (int p = 0; p < 8; ++p) {
        s += part[((long)b * 8 + p) * 256 + c];
        ss += part[65536 + ((long)b * 8 + p) * 256 + c];
    }
    float n = (float)lens[b];
    float m = s / n;
    float var = (ss - n * m * m) / (n - 1.0f);
    float sd = sqrtf(fmaxf(var, 1e-4f));
    __shared__ float mS[256], sS[256];
    mS[c] = m; sS[c] = sd;
    __syncthreads();
    float a0 = att_b1[c], a1 = 0.f;
    #pragma unroll 4
    for (int k = 0; k < 256; ++k) {
        a0 = fmaf(mS[k], att_w1[(256 + k) * 256 + c], a0);
        a1 = fmaf(sS[k], att_w1[(512 + k) * 256 + c], a1);
    }
    attbias[b * 256 + c] = a0 + a1;
}

// ------------- softmax-pool, phase 1: per-(b, chunk of 50) partials -------
// part layout: [mx | den | mu | m2], each [32][8][256], stride 65536
__global__ __launch_bounds__(256) void softmax_part_k(const float* __restrict__ logits,
    const float* __restrict__ h, const int* __restrict__ lens, float* __restrict__ part)
{
    int b = blockIdx.x, p = blockIdx.y, c = threadIdx.x;
    int len = lens[b];
    int t0 = p * 50, t1 = min(len, t0 + 50);
    int nt = t1 - t0;
    const float* lp = logits + ((long)b * 400 + t0) * 256 + c;
    const float* hp = h + ((long)b * 400 + t0) * 256 + c;
    float mx = -1e30f;
    for (int t = 0; t < nt; ++t) mx = fmaxf(mx, lp[(long)t * 256]);
    float den = 0.f, mu = 0.f, m2 = 0.f;
    for (int t = 0; t < nt; ++t) {
        float e = expf(lp[(long)t * 256] - mx);
        float hv = hp[(long)t * 256];
        den += e;
        mu = fmaf(e, hv, mu);
        m2 = fmaf(e * hv, hv, m2);
    }
    long o = ((long)b * 8 + p) * 256 + c;
    part[o] = mx; part[o + 65536] = den; part[o + 131072] = mu; part[o + 196608] = m2;
}

// ------------- softmax-pool, phase 2: combine + bn5 -> e5 -------
__global__ __launch_bounds__(256) void softmax_comb_k(const float* __restrict__ part,
    const float* __restrict__ bn5g, const float* __restrict__ bn5b, float* __restrict__ e5)
{
    int b = blockIdx.x, c = threadIdx.x;
    float mx[8], M = -1e30f;
    #pragma unroll
    for (int p = 0; p < 8; ++p) { mx[p] = part[((long)b * 8 + p) * 256 + c]; M = fmaxf(M, mx[p]); }
    float den = 0.f, mu = 0.f, m2 = 0.f;
    #pragma unroll
    for (int p = 0; p < 8; ++p) {
        long o = ((long)b * 8 + p) * 256 + c;
        float sc = expf(mx[p] - M);
        den = fmaf(part[o + 65536], sc, den);
        mu  = fmaf(part[o + 131072], sc, mu);
        m2  = fmaf(part[o + 196608], sc, m2);
    }
    mu /= den; m2 /= den;
    float sg = sqrtf(fmaxf(m2 - mu * mu, 1e-4f));
    e5[b * 512 + c]       = mu * bn5g[c] + bn5b[c];
    e5[b * 512 + 256 + c] = sg * bn5g[256 + c] + bn5b[256 + c];
}

// -------- fc6+bn6 -> emb(embG) ; L2-norm -> classify --------
__global__ __launch_bounds__(1024) void emb_k(const float* __restrict__ e5,
    const float* __restrict__ fc6w, const float* __restrict__ fc6b,
    const float* __restrict__ bn6g, const float* __restrict__ bn6b,
    const float* __restrict__ clsw, const float* __restrict__ clsb,
    float* __restrict__ classify, float* __restrict__ embG)
{
    int b = blockIdx.x, tid = threadIdx.x;
    int g = tid >> 8, c = tid & 255;
    __shared__ float es[512], embS[256], fP[4][256], red[4], cP[8][128];
    __shared__ float invS;
    if (tid < 512) es[tid] = e5[b * 512 + tid];
    __syncthreads();
    float acc = 0.f;
    for (int k = g * 128; k < g * 128 + 128; ++k)
        acc = fmaf(es[k], fc6w[k * 256 + c], acc);
    fP[g][c] = acc;
    __syncthreads();
    if (g == 0) {
        float e = fP[0][c] + fP[1][c] + fP[2][c] + fP[3][c] + fc6b[c];
        float eb = e * bn6g[c] + bn6b[c];
        embS[c] = eb;
        embG[b * 256 + c] = eb;
    }
    __syncthreads();
    if (tid < 256) {
        float sq = embS[tid] * embS[tid];
        for (int off = 32; off; off >>= 1) sq += __shfl_down(sq, off);
        if ((tid & 63) == 0) red[tid >> 6] = sq;
    }
    __syncthreads();
    if (tid == 0) invS = 1.0f / fmaxf(sqrtf(red[0] + red[1] + red[2] + red[3]), 1e-12f);
    __syncthreads();
    int g8 = tid >> 7, c7 = tid & 127;
    float a = 0.f;
    if (c7 < 101)
        for (int k = g8 * 32; k < g8 * 32 + 32; ++k)
            a = fmaf(embS[k], clsw[k * 101 + c7], a);
    cP[g8][c7] = a;
    __syncthreads();
    if (g8 == 0 && c7 < 101) {
        float ssum = 0.f;
        #pragma unroll
        for (int q = 0; q < 8; ++q) ssum += cP[q][c7];
        classify[b * 101 + c7] = ssum * invS + clsb[c7];
    }
}

// -------- arnvec[(i,b)] = embG[b] @ arn_w2[i] + arn_b[i] --------
__global__ __launch_bounds__(256) void arnvec_k(const float* __restrict__ embG,
    const float* __restrict__ arnw2, const float* __restrict__ arnb,
    float* __restrict__ arnvec)
{
    int i = blockIdx.x >> 5, b = blockIdx.x & 31, c = threadIdx.x;
    __shared__ float e[256];
    e[c] = embG[b * 256 + c];
    __syncthreads();
    const float* wp = arnw2 + (long)i * 65536;
    float a0 = arnb[i * 256 + c], a1 = 0.f;
    #pragma unroll 4
    for (int k = 0; k < 256; k += 2) {
        a0 = fmaf(e[k], wp[(long)k * 256 + c], a0);
        a1 = fmaf(e[k + 1], wp[(long)(k + 1) * 256 + c], a1);
    }
    arnvec[((long)i * 32 + b) * 256 + c] = a0 + a1;
}

// ---------------- overlap-add ----------------
__global__ __launch_bounds__(256) void ola_k(const float* __restrict__ y, float* __restrict__ out)
{
    int gidx = blockIdx.x * 256 + threadIdx.x;
    if (gidx >= 32 * 160000) return;
    int b = gidx / 160000;
    int p = gidx - b * 160000;
    int t0 = p / 160;
    int k0 = p - t0 * 160;
    const float* yb = y + (long)b * 1000 * 320;
    float v = yb[(long)t0 * 320 + k0];
    if (t0 > 0) { v += yb[(long)(t0 - 1) * 320 + k0 + 160]; v *= 0.5f; }
    out[gidx] = v;
}

extern "C" void kernel_launch(void* const* d_in, const int* in_sizes, int n_in,
                              void* d_out, int out_size, void* d_ws, size_t ws_size,
                              hipStream_t stream)
{
    (void)in_sizes; (void)n_in; (void)out_size; (void)ws_size;
    const float* input   = (const float*)d_in[0];
    const float* anchor  = (const float*)d_in[1];
    const int*   aux_len = (const int*)d_in[2];
    const float* in_w    = (const float*)d_in[4];
    const float* in_b    = (const float*)d_in[5];
    const float* out_w   = (const float*)d_in[6];
    const float* out_b   = (const float*)d_in[7];
    const float* gln_g   = (const float*)d_in[8];
    const float* gln_b   = (const float*)d_in[9];
    const float* ecapa_w = (const float*)d_in[10];
    const float* ecapa_b = (const float*)d_in[11];
    const float* att_w1  = (const float*)d_in[12];
    const float* att_b1  = (const float*)d_in[13];
    const float* attbn_g = (const float*)d_in[14];
    const float* attbn_b = (const float*)d_in[15];
    const float* att_w2  = (const float*)d_in[16];
    const float* att_b2  = (const float*)d_in[17];
    const float* bn5_g   = (const float*)d_in[18];
    const float* bn5_b   = (const float*)d_in[19];
    const float* fc6_w   = (const float*)d_in[20];
    const float* fc6_b   = (const float*)d_in[21];
    const float* bn6_g   = (const float*)d_in[22];
    const float* bn6_b   = (const float*)d_in[23];
    const float* cls_w   = (const float*)d_in[24];
    const float* cls_b   = (const float*)d_in[25];
    const float* arn_w1  = (const float*)d_in[26];
    const float* arn_w2  = (const float*)d_in[27];
    const float* arn_b   = (const float*)d_in[28];

    float* out_sig = (float*)d_out;
    float* out_cls = out_sig + (long)32 * 160000;

    float* ws = (float*)d_ws;
    float* o0     = ws;                    // [32000,256]
    float* oB     = ws + 8192000;          // ARN ping-pong / later y; also gln/stats parts
    float* aux    = ws + 16384000;         // [12800,256], reused as logits
    float* logits = aux;
    float* h      = ws + 19660800;         // [12800,256]
    float* a2     = ws + 22937600;         // [12800,256]; reused as softmax parts
    short* WT     = (short*)(ws + 26214400);  // 638976 bf16
    float* smalls = ws + 26533888;
    float* meanA   = smalls;               // 32
    float* rstdA   = smalls + 32;          // 32
    float* attbias = smalls + 64;          // 8192
    float* e5      = smalls + 64 + 8192;   // 16384
    float* arnvec  = e5 + 16384;           // 32768
    float* uArr    = arnvec + 32768;       // 256
    float* vArr    = uArr + 256;           // 256
    float* embG    = vArr + 256;           // 8192
    float* y       = oB;                   // [32000,320] (oB dead by then)
    float* glnpart = oB;                   // 1024 (dead before ARN)
    float* stpart  = oB;                   // 131072 (dead before ARN)
    float* smpart  = a2;                   // 262144 (a2 dead after logits GEMM)

    short* WT_in  = WT;            // [256][320]
    short* WT_ec  = WT + 81920;    // [256][256] g-scaled
    short* WT_a1  = WT + 147456;
    short* WT_a2  = WT + 212992;
    short* WT_arn = WT + 278528;   // 4x[256][256]
    short* WT_out = WT + 540672;   // [384][256] padded

    dim3 blk(256);

    convert_wt_k<<<dim3(2496), blk, 0, stream>>>(in_w, ecapa_w, att_w1, att_w2, arn_w1, out_w, gln_g, WT);
    glnuv_k<<<dim3(1), blk, 0, stream>>>(ecapa_w, gln_g, gln_b, ecapa_b, uArr, vArr);

    // frames @ in_w + in_b -> o0
    mfma_gemm_k<1, 0, 1000><<<dim3(2, 250), blk, 0, stream>>>(input, WT_in, in_b, o0,
        nullptr, nullptr, nullptr, nullptr, nullptr, nullptr, nullptr, 320, 256, 160000);
    // aux frames @ in_w + in_b -> aux
    mfma_gemm_k<1, 0, 400><<<dim3(2, 100), blk, 0, stream>>>(anchor, WT_in, in_b, aux,
        nullptr, nullptr, nullptr, nullptr, nullptr, nullptr, nullptr, 320, 256, 64000);
    // GLN stats (two-phase)
    gln_part_k<<<dim3(32, 16), blk, 0, stream>>>(aux, aux_len, glnpart);
    gln_comb_k<<<dim3(1), dim3(512), 0, stream>>>(glnpart, aux_len, meanA, rstdA);
    // h = relu(rstd*(aux@W' - mean*u) + v) * mask   (EPI 5)
    mfma_gemm_k<0, 5, 400><<<dim3(2, 100), blk, 0, stream>>>(aux, WT_ec, nullptr, h,
        nullptr, nullptr, uArr, vArr, meanA, rstdA, aux_len, 256, 256, 0);
    // time stats + attbias (two-phase)
    stats_part_k<<<dim3(32, 8), blk, 0, stream>>>(h, aux_len, stpart);
    stats_comb_k<<<dim3(32), blk, 0, stream>>>(stpart, aux_len, att_w1, att_b1, attbias);
    // a2 = tanh(relu(h @ W1h + attbias) * attbn_g + attbn_b)
    mfma_gemm_k<0, 2, 400><<<dim3(2, 100), blk, 0, stream>>>(h, WT_a1, nullptr, a2,
        nullptr, attbias, attbn_g, attbn_b, nullptr, nullptr, nullptr, 256, 256, 0);
    // logits = a2 @ att_w2 + att_b2
    mfma_gemm_k<0, 0, 400><<<dim3(2, 100), blk, 0, stream>>>(a2, WT_a2, att_b2, logits,
        nullptr, nullptr, nullptr, nullptr, nullptr, nullptr, nullptr, 256, 256, 0);
    // softmax + pooling (two-phase)
    softmax_part_k<<<dim3(32, 8), blk, 0, stream>>>(logits, h, aux_len, smpart);
    softmax_comb_k<<<dim3(32), blk, 0, stream>>>(smpart, bn5_g, bn5_b, e5);
    // emb pipeline
    emb_k<<<dim3(32), dim3(1024), 0, stream>>>(e5, fc6_w, fc6_b, bn6_g, bn6_b, cls_w, cls_b,
                                               out_cls, embG);
    arnvec_k<<<dim3(128), blk, 0, stream>>>(embG, arn_w2, arn_b, arnvec);
    // 4 ARN blocks, ping-pong (final in o0)
    float* bufs[2] = { o0, oB };
    for (int i = 0; i < 4; ++i) {
        const float* src = bufs[i & 1];
        float* dst = bufs[(i + 1) & 1];
        mfma_gemm_k<0, 4, 1000><<<dim3(2, 250), blk, 0, stream>>>(src, WT_arn + i * 65536,
            nullptr, dst, src, arnvec + i * 8192,
            nullptr, nullptr, nullptr, nullptr, nullptr, 256, 256, 0);
    }
    // y = o0 @ out_w + out_b  [32000,320]
    mfma_gemm_k<0, 0, 1000><<<dim3(3, 250), blk, 0, stream>>>(o0, WT_out, out_b, y,
        nullptr, nullptr, nullptr, nullptr, nullptr, nullptr, nullptr, 256, 320, 0);
    ola_k<<<dim3(20000), blk, 0, stream>>>(y, out_sig);
}

// Round 5
// 390.025 us; speedup vs baseline: 2.8350x; 1.3097x over previous
//
#include <hip/hip_runtime.h>
#include <math.h>

typedef __attribute__((ext_vector_type(4))) float f32x4;
typedef __attribute__((ext_vector_type(8))) short short8;
typedef __attribute__((ext_vector_type(4))) short bf16x4;

__device__ __forceinline__ short f2bf(float f) {
    unsigned u = __builtin_bit_cast(unsigned, f);
    u += 0x7FFFu + ((u >> 16) & 1u);          // RNE (inputs finite)
    return (short)(u >> 16);
}
__device__ __forceinline__ float bf2f(short s) {
    unsigned u = ((unsigned)(unsigned short)s) << 16;
    return __builtin_bit_cast(float, u);
}
__device__ __forceinline__ short8 pack8(const float* x) {
    short8 r;
    #pragma unroll
    for (int i = 0; i < 8; ++i) r[i] = f2bf(x[i]);
    return r;
}
__device__ __forceinline__ void load16(const float* p, float* x) {
    const float4* q = (const float4*)p;
    #pragma unroll
    for (int i = 0; i < 4; ++i) {
        float4 v = q[i];
        x[i*4+0] = v.x; x[i*4+1] = v.y; x[i*4+2] = v.z; x[i*4+3] = v.w;
    }
}
__device__ __forceinline__ float fast_tanh(float x) {
    float cx = fminf(fmaxf(x, -9.f), 9.f);
    float e = __expf(2.f * cx);
    return (e - 1.f) / (e + 1.f);
}

// ---------------- weight transpose+convert: WT[n][k] bf16 <- W[k][n] f32 ----
__global__ __launch_bounds__(256) void convert_wt_k(
    const float* __restrict__ in_w, const float* __restrict__ ecapa_w,
    const float* __restrict__ att_w1, const float* __restrict__ att_w2,
    const float* __restrict__ arn_w1, const float* __restrict__ out_w,
    const float* __restrict__ gln_g, short* __restrict__ WT)
{
    int id = blockIdx.x * 256 + threadIdx.x;
    if (id < 81920) { int n = id / 320, k = id - n * 320; WT[id] = f2bf(in_w[k * 256 + n]); return; }
    id -= 81920;
    if (id < 65536) { int n = id >> 8, k = id & 255; WT[81920 + (n << 8) + k] = f2bf(gln_g[k] * ecapa_w[k * 256 + n]); return; }
    id -= 65536;
    if (id < 65536) { int n = id >> 8, k = id & 255; WT[147456 + (n << 8) + k] = f2bf(att_w1[k * 256 + n]); return; }
    id -= 65536;
    if (id < 65536) { int n = id >> 8, k = id & 255; WT[212992 + (n << 8) + k] = f2bf(att_w2[k * 256 + n]); return; }
    id -= 65536;
    if (id < 262144) {
        int i = id >> 16, r = id & 65535, n = r >> 8, k = r & 255;
        WT[278528 + id] = f2bf(arn_w1[i * 65536 + k * 256 + n]); return;
    }
    id -= 262144;
    if (id < 98304) {
        int n = id >> 8, k = id & 255;
        WT[540672 + id] = (n < 320) ? f2bf(out_w[k * 320 + n]) : (short)0; return;
    }
}

// u[n] = sum_k g[k] W[k][n] ; v[n] = sum_k gb[k] W[k][n] + ecapa_b[n]
__global__ __launch_bounds__(256) void glnuv_k(const float* __restrict__ ecapa_w,
    const float* __restrict__ gln_g, const float* __restrict__ gln_b,
    const float* __restrict__ ecapa_b, float* __restrict__ uArr, float* __restrict__ vArr)
{
    int n = threadIdx.x;
    float u = 0.f, v = 0.f;
    #pragma unroll 8
    for (int k = 0; k < 256; ++k) {
        float w = ecapa_w[k * 256 + n];
        u = fmaf(gln_g[k], w, u);
        v = fmaf(gln_b[k], w, v);
    }
    uArr[n] = u;
    vArr[n] = v + ecapa_b[n];
}

// ---------------- bf16 MFMA GEMM (swapped-operand C layout) ----------------
// C-frag per lane (fr,fc): row = m0+wm*64+fr*16+(lane&15),
//                          cols = n0+wn*64+fc*16+(lane>>4)*4 + 0..3
template<int AMODE, int EPI, int TPB, int OUTBF>
__global__ __launch_bounds__(256) void mfma_gemm_k(
    const float* __restrict__ Asrc, const short* __restrict__ WT,
    const float* __restrict__ bias, void* __restrict__ Cv,
    const float* __restrict__ rowvec,
    const float* __restrict__ ng0, const float* __restrict__ ng1,
    const float* __restrict__ stat0, const float* __restrict__ stat1,
    const int* __restrict__ lens,
    int K, int N, int Lsig)
{
    __shared__ short As[128 * 32];
    __shared__ short Bs[128 * 32];
    const int tid = threadIdx.x;
    const int n0 = blockIdx.x * 128, m0 = blockIdx.y * 128;
    const int rl = tid >> 1, kh = tid & 1;
    const int lane = tid & 63, w = tid >> 6;
    const int wm = w >> 1, wn = w & 1;
    const int lr = lane & 15, ls = lane >> 4;

    const int arow = m0 + rl;
    const float* aptr;
    int tt = 0;
    if (AMODE == 0) {
        aptr = Asrc + (long)arow * K;
    } else {
        int b = arow / TPB; tt = arow - b * TPB;
        aptr = Asrc + (long)b * Lsig + 160 * tt;
    }
    const short* bsrc = WT + (long)(n0 + rl) * K;

    const int s0 = (2 * kh) ^ (rl & 3), s1 = (2 * kh + 1) ^ (rl & 3);
    short* aw0 = &As[rl * 32 + s0 * 8]; short* aw1 = &As[rl * 32 + s1 * 8];
    short* bw0 = &Bs[rl * 32 + s0 * 8]; short* bw1 = &Bs[rl * 32 + s1 * 8];
    const int rco = (ls ^ (lr & 3)) * 8;

    f32x4 acc[4][4] = {};
    float x[16];
    short8 blo, bhi;

    {
        const int kk = kh * 16;
        if (AMODE == 0) {
            load16(aptr + kk, x);
        } else {
            int base = 160 * tt + kk;
            if (base + 15 < Lsig) load16(aptr + kk, x);
            else {
                #pragma unroll
                for (int e = 0; e < 16; ++e) x[e] = (base + e < Lsig) ? aptr[kk + e] : 0.f;
            }
        }
        blo = *(const short8*)(bsrc + kk);
        bhi = *(const short8*)(bsrc + kk + 8);
    }

    for (int k0 = 0; k0 < K; k0 += 32) {
        *(short8*)aw0 = pack8(x);
        *(short8*)aw1 = pack8(x + 8);
        *(short8*)bw0 = blo;
        *(short8*)bw1 = bhi;
        __syncthreads();
        if (k0 + 32 < K) {
            const int kk = k0 + 32 + kh * 16;
            if (AMODE == 0) {
                load16(aptr + kk, x);
            } else {
                int base = 160 * tt + kk;
                if (base + 15 < Lsig) load16(aptr + kk, x);
                else {
                    #pragma unroll
                    for (int e = 0; e < 16; ++e) x[e] = (base + e < Lsig) ? aptr[kk + e] : 0.f;
                }
            }
            blo = *(const short8*)(bsrc + kk);
            bhi = *(const short8*)(bsrc + kk + 8);
        }
        short8 af[4], bfr[4];
        #pragma unroll
        for (int f = 0; f < 4; ++f) {
            af[f]  = *(const short8*)&As[(wm * 64 + f * 16 + lr) * 32 + rco];
            bfr[f] = *(const short8*)&Bs[(wn * 64 + f * 16 + lr) * 32 + rco];
        }
        #pragma unroll
        for (int fr = 0; fr < 4; ++fr)
            #pragma unroll
            for (int fc = 0; fc < 4; ++fc)
                acc[fr][fc] = __builtin_amdgcn_mfma_f32_16x16x32_bf16(bfr[fc], af[fr], acc[fr][fc], 0, 0, 0);
        __syncthreads();
    }

    #pragma unroll
    for (int fr = 0; fr < 4; ++fr) {
        const int row = m0 + wm * 64 + fr * 16 + lr;
        int bb = 0, tloc = 0;
        if (EPI != 0) { bb = row / TPB; tloc = row - bb * TPB; }
        float mean = 0.f, rstd = 0.f; int lenb = 0;
        if (EPI == 5) { mean = stat0[bb]; rstd = stat1[bb]; lenb = lens[bb]; }
        #pragma unroll
        for (int fc = 0; fc < 4; ++fc) {
            const int col = n0 + wn * 64 + fc * 16 + ls * 4;
            if (col >= N) continue;
            f32x4 a = acc[fr][fc];
            float4 r;
            if (EPI == 0) {
                float4 bv = *(const float4*)(bias + col);
                r.x = a[0] + bv.x; r.y = a[1] + bv.y; r.z = a[2] + bv.z; r.w = a[3] + bv.w;
            } else if (EPI == 2) {
                float4 rvv = *(const float4*)(rowvec + bb * 256 + col);
                float4 g0 = *(const float4*)(ng0 + col);
                float4 g1 = *(const float4*)(ng1 + col);
                r.x = fast_tanh(fmaxf(a[0] + rvv.x, 0.f) * g0.x + g1.x);
                r.y = fast_tanh(fmaxf(a[1] + rvv.y, 0.f) * g0.y + g1.y);
                r.z = fast_tanh(fmaxf(a[2] + rvv.z, 0.f) * g0.z + g1.z);
                r.w = fast_tanh(fmaxf(a[3] + rvv.w, 0.f) * g0.w + g1.w);
            } else { // EPI 5
                float4 uu = *(const float4*)(ng0 + col);
                float4 vv = *(const float4*)(ng1 + col);
                bool val = tloc < lenb;
                r.x = val ? fmaxf(rstd * (a[0] - mean * uu.x) + vv.x, 0.f) : 0.f;
                r.y = val ? fmaxf(rstd * (a[1] - mean * uu.y) + vv.y, 0.f) : 0.f;
                r.z = val ? fmaxf(rstd * (a[2] - mean * uu.z) + vv.z, 0.f) : 0.f;
                r.w = val ? fmaxf(rstd * (a[3] - mean * uu.w) + vv.w, 0.f) : 0.f;
            }
            if (OUTBF) {
                bf16x4 o; o[0] = f2bf(r.x); o[1] = f2bf(r.y); o[2] = f2bf(r.z); o[3] = f2bf(r.w);
                *(bf16x4*)((short*)Cv + (long)row * N + col) = o;
            } else {
                *(float4*)((float*)Cv + (long)row * N + col) = r;
            }
        }
    }
}

// ------ fused 4x ARN + out_w projection ------
__global__ __launch_bounds__(512) void arn_fused_k(
    const short* __restrict__ o0b, const short* __restrict__ WT_arn,
    const short* __restrict__ WT_out, const float* __restrict__ out_b,
    const float* __restrict__ arnvec, float* __restrict__ y)
{
    __shared__ short Tb[2][128 * 256];
    const int tid = threadIdx.x;
    const int m0 = blockIdx.x * 128;
    const int lane = tid & 63, w = tid >> 6;
    const int wm = w >> 2, wn = w & 3;
    const int lr = lane & 15, ls = lane >> 4;

    {
        int row = tid >> 2, q = (tid & 3) * 8;
        const short* src = o0b + (long)(m0 + row) * 256 + q * 8;
        #pragma unroll
        for (int s = 0; s < 8; ++s) {
            short8 v = *(const short8*)(src + s * 8);
            int slot = q + s;
            *(short8*)&Tb[0][row * 256 + ((slot ^ (row & 7)) << 3)] = v;
        }
    }
    __syncthreads();

    f32x4 r[4][4];
    #pragma unroll
    for (int fr = 0; fr < 4; ++fr) {
        int row = wm * 64 + fr * 16 + lr;
        #pragma unroll
        for (int fc = 0; fc < 4; ++fc) {
            int col = wn * 64 + fc * 16 + ls * 4;
            int slot = col >> 3, off = col & 7;
            bf16x4 v = *(const bf16x4*)&Tb[0][row * 256 + ((slot ^ (row & 7)) << 3) + off];
            r[fr][fc][0] = bf2f(v[0]); r[fr][fc][1] = bf2f(v[1]);
            r[fr][fc][2] = bf2f(v[2]); r[fr][fc][3] = bf2f(v[3]);
        }
    }

    int cur = 0;
    for (int i = 0; i < 4; ++i) {
        const short* Wl = WT_arn + (long)i * 65536;
        const float* rv = arnvec + (long)i * 8192;
        f32x4 acc[4][4] = {};
        #pragma unroll
        for (int ks = 0; ks < 8; ++ks) {
            short8 af[4], bq[4];
            #pragma unroll
            for (int fr = 0; fr < 4; ++fr) {
                int row = wm * 64 + fr * 16 + lr;
                int slot = ks * 4 + ls;
                af[fr] = *(const short8*)&Tb[cur][row * 256 + ((slot ^ (row & 7)) << 3)];
            }
            #pragma unroll
            for (int fc = 0; fc < 4; ++fc) {
                int n = wn * 64 + fc * 16 + lr;
                bq[fc] = *(const short8*)(Wl + n * 256 + ks * 32 + ls * 8);
            }
            #pragma unroll
            for (int fr = 0; fr < 4; ++fr)
                #pragma unroll
                for (int fc = 0; fc < 4; ++fc)
                    acc[fr][fc] = __builtin_amdgcn_mfma_f32_16x16x32_bf16(bq[fc], af[fr], acc[fr][fc], 0, 0, 0);
        }
        #pragma unroll
        for (int fr = 0; fr < 4; ++fr) {
            int rowl = wm * 64 + fr * 16 + lr;
            int bb = (m0 + rowl) / 1000;
            #pragma unroll
            for (int fc = 0; fc < 4; ++fc) {
                int col = wn * 64 + fc * 16 + ls * 4;
                float4 rvv = *(const float4*)(rv + bb * 256 + col);
                f32x4 a = acc[fr][fc];
                r[fr][fc][0] += fast_tanh(a[0] + rvv.x);
                r[fr][fc][1] += fast_tanh(a[1] + rvv.y);
                r[fr][fc][2] += fast_tanh(a[2] + rvv.z);
                r[fr][fc][3] += fast_tanh(a[3] + rvv.w);
                bf16x4 o;
                o[0] = f2bf(r[fr][fc][0]); o[1] = f2bf(r[fr][fc][1]);
                o[2] = f2bf(r[fr][fc][2]); o[3] = f2bf(r[fr][fc][3]);
                int slot = col >> 3, off = col & 7;
                *(bf16x4*)&Tb[cur ^ 1][rowl * 256 + ((slot ^ (rowl & 7)) << 3) + off] = o;
            }
        }
        cur ^= 1;
        __syncthreads();
    }

    f32x4 pacc[5][4] = {};
    #pragma unroll
    for (int ks = 0; ks < 8; ++ks) {
        short8 af[4];
        #pragma unroll
        for (int fr = 0; fr < 4; ++fr) {
            int row = wm * 64 + fr * 16 + lr;
            int slot = ks * 4 + ls;
            af[fr] = *(const short8*)&Tb[cur][row * 256 + ((slot ^ (row & 7)) << 3)];
        }
        #pragma unroll
        for (int fc = 0; fc < 5; ++fc) {
            int n = wn * 80 + fc * 16 + lr;
            short8 bq = *(const short8*)(WT_out + n * 256 + ks * 32 + ls * 8);
            #pragma unroll
            for (int fr = 0; fr < 4; ++fr)
                pacc[fc][fr] = __builtin_amdgcn_mfma_f32_16x16x32_bf16(bq, af[fr], pacc[fc][fr], 0, 0, 0);
        }
    }
    #pragma unroll
    for (int fc = 0; fc < 5; ++fc) {
        #pragma unroll
        for (int fr = 0; fr < 4; ++fr) {
            int row = m0 + wm * 64 + fr * 16 + lr;
            int cb = wn * 80 + fc * 16 + ls * 4;
            float4 ob = *(const float4*)(out_b + cb);
            f32x4 a = pacc[fc][fr];
            float4 o;
            o.x = a[0] + ob.x; o.y = a[1] + ob.y; o.z = a[2] + ob.z; o.w = a[3] + ob.w;
            *(float4*)(y + (long)row * 320 + cb) = o;
        }
    }
}

// ------------- GLN stats, phase 1 -------
__global__ __launch_bounds__(256) void gln_part_k(const float* __restrict__ aux,
    const int* __restrict__ lens, float* __restrict__ part)
{
    int b = blockIdx.x, p = blockIdx.y, tid = threadIdx.x;
    int len = lens[b];
    int t0 = p * 25, t1 = min(len, t0 + 25);
    const float4* src = (const float4*)(aux + (long)b * 400 * 256);
    float s = 0.f, ss = 0.f;
    for (int i = t0 * 64 + tid; i < t1 * 64; i += 256) {
        float4 v = src[i];
        s += v.x + v.y + v.z + v.w;
        ss += v.x*v.x + v.y*v.y + v.z*v.z + v.w*v.w;
    }
    for (int off = 32; off; off >>= 1) { s += __shfl_down(s, off); ss += __shfl_down(ss, off); }
    __shared__ float l1[4], l2[4];
    if ((tid & 63) == 0) { l1[tid >> 6] = s; l2[tid >> 6] = ss; }
    __syncthreads();
    if (tid == 0) {
        part[b * 16 + p]       = l1[0] + l1[1] + l1[2] + l1[3];
        part[512 + b * 16 + p] = l2[0] + l2[1] + l2[2] + l2[3];
    }
}

// ------------- GLN stats, phase 2 -------
__global__ __launch_bounds__(512) void gln_comb_k(const float* __restrict__ part,
    const int* __restrict__ lens, float* __restrict__ meanA, float* __restrict__ rstdA)
{
    __shared__ float s1[32][16], s2[32][16];
    int tid = threadIdx.x, b = tid >> 4, p = tid & 15;
    s1[b][p] = part[b * 16 + p];
    s2[b][p] = part[512 + b * 16 + p];
    __syncthreads();
    if (tid < 32) {
        float s = 0.f, ss = 0.f;
        for (int q = 0; q < 16; ++q) { s += s1[tid][q]; ss += s2[tid][q]; }
        float cnt = (float)lens[tid] * 256.f;
        float mean = s / cnt;
        float var = ss / cnt - mean * mean;
        meanA[tid] = mean;
        rstdA[tid] = 1.0f / sqrtf(var + 1e-5f);
    }
}

// ------------- time stats, phase 1 -------
__global__ __launch_bounds__(256) void stats_part_k(const float* __restrict__ h,
    const int* __restrict__ lens, float* __restrict__ part)
{
    int b = blockIdx.x, p = blockIdx.y, c = threadIdx.x;
    int len = lens[b];
    int t0 = p * 50, t1 = min(len, t0 + 50);
    const float* hp = h + ((long)b * 400 + t0) * 256 + c;
    float s = 0.f, ss = 0.f;
    for (int t = 0; t < t1 - t0; ++t) { float v = hp[(long)t * 256]; s += v; ss = fmaf(v, v, ss); }
    part[((long)b * 8 + p) * 256 + c] = s;
    part[65536 + ((long)b * 8 + p) * 256 + c] = ss;
}

// ------------- time stats, phase 2 -------
__global__ __launch_bounds__(256) void stats_comb_k(const float* __restrict__ part,
    const int* __restrict__ lens, const float* __restrict__ att_w1,
    const float* __restrict__ att_b1, float* __restrict__ attbias)
{
    int b = blockIdx.x, c = threadIdx.x;
    float s = 0.f, ss = 0.f;
    #pragma unroll
    for (int p = 0; p < 8; ++p) {
        s += part[((long)b * 8 + p) * 256 + c];
        ss += part[65536 + ((long)b * 8 + p) * 256 + c];
    }
    float n = (float)lens[b];
    float m = s / n;
    float var = (ss - n * m * m) / (n - 1.0f);
    float sd = sqrtf(fmaxf(var, 1e-4f));
    __shared__ float mS[256], sS[256];
    mS[c] = m; sS[c] = sd;
    __syncthreads();
    float a0 = att_b1[c], a1 = 0.f;
    #pragma unroll 4
    for (int k = 0; k < 256; ++k) {
        a0 = fmaf(mS[k], att_w1[(256 + k) * 256 + c], a0);
        a1 = fmaf(sS[k], att_w1[(512 + k) * 256 + c], a1);
    }
    attbias[b * 256 + c] = a0 + a1;
}

// ------------- softmax-pool, phase 1 -------
__global__ __launch_bounds__(256) void softmax_part_k(const float* __restrict__ logits,
    const float* __restrict__ h, const int* __restrict__ lens, float* __restrict__ part)
{
    int b = blockIdx.x, p = blockIdx.y, c = threadIdx.x;
    int len = lens[b];
    int t0 = p * 50, t1 = min(len, t0 + 50);
    int nt = t1 - t0;
    const float* lp = logits + ((long)b * 400 + t0) * 256 + c;
    const float* hp = h + ((long)b * 400 + t0) * 256 + c;
    float mx = -1e30f;
    for (int t = 0; t < nt; ++t) mx = fmaxf(mx, lp[(long)t * 256]);
    float den = 0.f, mu = 0.f, m2 = 0.f;
    for (int t = 0; t < nt; ++t) {
        float e = __expf(lp[(long)t * 256] - mx);
        float hv = hp[(long)t * 256];
        den += e;
        mu = fmaf(e, hv, mu);
        m2 = fmaf(e * hv, hv, m2);
    }
    long o = ((long)b * 8 + p) * 256 + c;
    part[o] = mx; part[o + 65536] = den; part[o + 131072] = mu; part[o + 196608] = m2;
}

// ------------- softmax-pool, phase 2 -------
__global__ __launch_bounds__(256) void softmax_comb_k(const float* __restrict__ part,
    const float* __restrict__ bn5g, const float* __restrict__ bn5b, float* __restrict__ e5)
{
    int b = blockIdx.x, c = threadIdx.x;
    float mx[8], M = -1e30f;
    #pragma unroll
    for (int p = 0; p < 8; ++p) { mx[p] = part[((long)b * 8 + p) * 256 + c]; M = fmaxf(M, mx[p]); }
    float den = 0.f, mu = 0.f, m2 = 0.f;
    #pragma unroll
    for (int p = 0; p < 8; ++p) {
        long o = ((long)b * 8 + p) * 256 + c;
        float sc = __expf(mx[p] - M);
        den = fmaf(part[o + 65536], sc, den);
        mu  = fmaf(part[o + 131072], sc, mu);
        m2  = fmaf(part[o + 196608], sc, m2);
    }
    mu /= den; m2 /= den;
    float sg = sqrtf(fmaxf(m2 - mu * mu, 1e-4f));
    e5[b * 512 + c]       = mu * bn5g[c] + bn5b[c];
    e5[b * 512 + 256 + c] = sg * bn5g[256 + c] + bn5b[256 + c];
}

// -------- fc6+bn6 -> emb(embG) ; L2-norm -> classify --------
__global__ __launch_bounds__(1024) void emb_k(const float* __restrict__ e5,
    const float* __restrict__ fc6w, const float* __restrict__ fc6b,
    const float* __restrict__ bn6g, const float* __restrict__ bn6b,
    const float* __restrict__ clsw, const float* __restrict__ clsb,
    float* __restrict__ classify, float* __restrict__ embG)
{
    int b = blockIdx.x, tid = threadIdx.x;
    int g = tid >> 8, c = tid & 255;
    __shared__ float es[512], embS[256], fP[4][256], red[4], cP[8][128];
    __shared__ float invS;
    if (tid < 512) es[tid] = e5[b * 512 + tid];
    __syncthreads();
    float acc = 0.f;
    for (int k = g * 128; k < g * 128 + 128; ++k)
        acc = fmaf(es[k], fc6w[k * 256 + c], acc);
    fP[g][c] = acc;
    __syncthreads();
    if (g == 0) {
        float e = fP[0][c] + fP[1][c] + fP[2][c] + fP[3][c] + fc6b[c];
        float eb = e * bn6g[c] + bn6b[c];
        embS[c] = eb;
        embG[b * 256 + c] = eb;
    }
    __syncthreads();
    if (tid < 256) {
        float sq = embS[tid] * embS[tid];
        for (int off = 32; off; off >>= 1) sq += __shfl_down(sq, off);
        if ((tid & 63) == 0) red[tid >> 6] = sq;
    }
    __syncthreads();
    if (tid == 0) invS = 1.0f / fmaxf(sqrtf(red[0] + red[1] + red[2] + red[3]), 1e-12f);
    __syncthreads();
    int g8 = tid >> 7, c7 = tid & 127;
    float a = 0.f;
    if (c7 < 101)
        for (int k = g8 * 32; k < g8 * 32 + 32; ++k)
            a = fmaf(embS[k], clsw[k * 101 + c7], a);
    cP[g8][c7] = a;
    __syncthreads();
    if (g8 == 0 && c7 < 101) {
        float ssum = 0.f;
        #pragma unroll
        for (int q = 0; q < 8; ++q) ssum += cP[q][c7];
        classify[b * 101 + c7] = ssum * invS + clsb[c7];
    }
}

// -------- arnvec --------
__global__ __launch_bounds__(256) void arnvec_k(const float* __restrict__ embG,
    const float* __restrict__ arnw2, const float* __restrict__ arnb,
    float* __restrict__ arnvec)
{
    int i = blockIdx.x >> 5, b = blockIdx.x & 31, c = threadIdx.x;
    __shared__ float e[256];
    e[c] = embG[b * 256 + c];
    __syncthreads();
    const float* wp = arnw2 + (long)i * 65536;
    float a0 = arnb[i * 256 + c], a1 = 0.f;
    #pragma unroll 4
    for (int k = 0; k < 256; k += 2) {
        a0 = fmaf(e[k], wp[(long)k * 256 + c], a0);
        a1 = fmaf(e[k + 1], wp[(long)(k + 1) * 256 + c], a1);
    }
    arnvec[((long)i * 32 + b) * 256 + c] = a0 + a1;
}

// ---------------- overlap-add ----------------
__global__ __launch_bounds__(256) void ola_k(const float* __restrict__ y, float* __restrict__ out)
{
    int gidx = blockIdx.x * 256 + threadIdx.x;
    if (gidx >= 32 * 160000) return;
    int b = gidx / 160000;
    int p = gidx - b * 160000;
    int t0 = p / 160;
    int k0 = p - t0 * 160;
    const float* yb = y + (long)b * 1000 * 320;
    float v = yb[(long)t0 * 320 + k0];
    if (t0 > 0) { v += yb[(long)(t0 - 1) * 320 + k0 + 160]; v *= 0.5f; }
    out[gidx] = v;
}

extern "C" void kernel_launch(void* const* d_in, const int* in_sizes, int n_in,
                              void* d_out, int out_size, void* d_ws, size_t ws_size,
                              hipStream_t stream)
{
    (void)in_sizes; (void)n_in; (void)out_size; (void)ws_size;
    const float* input   = (const float*)d_in[0];
    const float* anchor  = (const float*)d_in[1];
    const int*   aux_len = (const int*)d_in[2];
    const float* in_w    = (const float*)d_in[4];
    const float* in_b    = (const float*)d_in[5];
    const float* out_w   = (const float*)d_in[6];
    const float* out_b   = (const float*)d_in[7];
    const float* gln_g   = (const float*)d_in[8];
    const float* gln_b   = (const float*)d_in[9];
    const float* ecapa_w = (const float*)d_in[10];
    const float* ecapa_b = (const float*)d_in[11];
    const float* att_w1  = (const float*)d_in[12];
    const float* att_b1  = (const float*)d_in[13];
    const float* attbn_g = (const float*)d_in[14];
    const float* attbn_b = (const float*)d_in[15];
    const float* att_w2  = (const float*)d_in[16];
    const float* att_b2  = (const float*)d_in[17];
    const float* bn5_g   = (const float*)d_in[18];
    const float* bn5_b   = (const float*)d_in[19];
    const float* fc6_w   = (const float*)d_in[20];
    const float* fc6_b   = (const float*)d_in[21];
    const float* bn6_g   = (const float*)d_in[22];
    const float* bn6_b   = (const float*)d_in[23];
    const float* cls_w   = (const float*)d_in[24];
    const float* cls_b   = (const float*)d_in[25];
    const float* arn_w1  = (const float*)d_in[26];
    const float* arn_w2  = (const float*)d_in[27];
    const float* arn_b   = (const float*)d_in[28];

    float* out_sig = (float*)d_out;
    float* out_cls = out_sig + (long)32 * 160000;

    // workspace layout (floats). o0b is [32000][256] bf16 = 8.192M shorts
    // = 4,096,000 FLOATS (round-4 bug: was counted as 2,048,000).
    float* ws = (float*)d_ws;
    short* o0b    = (short*)ws;            // ws[0 .. 4,096,000)
    float* aux    = ws + 4096000;          // [12800,256] f32 (reused as logits)
    float* logits = aux;
    float* h      = ws + 7372800;          // [12800,256]
    float* a2     = ws + 10649600;         // [12800,256]
    float* y      = ws + 13926400;         // [32000,320] f32, ends 24,166,400
    float* glnpart = y;                    // 1024   (dead before y written)
    float* stpart  = y + 4096;             // 131072 (dead before y written)
    float* smpart  = y + 140000;           // 262144 (dead before y written)
    short* WT     = (short*)(ws + 24166400);  // 638,976 shorts = 319,488 floats
    float* smalls = ws + 24485888;
    float* meanA   = smalls;
    float* rstdA   = smalls + 32;
    float* attbias = smalls + 64;
    float* e5      = smalls + 64 + 8192;
    float* arnvec  = e5 + 16384;
    float* uArr    = arnvec + 32768;
    float* vArr    = uArr + 256;
    float* embG    = vArr + 256;

    short* WT_in  = WT;
    short* WT_ec  = WT + 81920;
    short* WT_a1  = WT + 147456;
    short* WT_a2  = WT + 212992;
    short* WT_arn = WT + 278528;
    short* WT_out = WT + 540672;

    dim3 blk(256);

    convert_wt_k<<<dim3(2496), blk, 0, stream>>>(in_w, ecapa_w, att_w1, att_w2, arn_w1, out_w, gln_g, WT);
    glnuv_k<<<dim3(1), blk, 0, stream>>>(ecapa_w, gln_g, gln_b, ecapa_b, uArr, vArr);

    mfma_gemm_k<1, 0, 1000, 1><<<dim3(2, 250), blk, 0, stream>>>(input, WT_in, in_b, o0b,
        nullptr, nullptr, nullptr, nullptr, nullptr, nullptr, 320, 256, 160000);
    mfma_gemm_k<1, 0, 400, 0><<<dim3(2, 100), blk, 0, stream>>>(anchor, WT_in, in_b, aux,
        nullptr, nullptr, nullptr, nullptr, nullptr, nullptr, 320, 256, 64000);
    gln_part_k<<<dim3(32, 16), blk, 0, stream>>>(aux, aux_len, glnpart);
    gln_comb_k<<<dim3(1), dim3(512), 0, stream>>>(glnpart, aux_len, meanA, rstdA);
    mfma_gemm_k<0, 5, 400, 0><<<dim3(2, 100), blk, 0, stream>>>(aux, WT_ec, nullptr, h,
        nullptr, uArr, vArr, meanA, rstdA, aux_len, 256, 256, 0);
    stats_part_k<<<dim3(32, 8), blk, 0, stream>>>(h, aux_len, stpart);
    stats_comb_k<<<dim3(32), blk, 0, stream>>>(stpart, aux_len, att_w1, att_b1, attbias);
    mfma_gemm_k<0, 2, 400, 0><<<dim3(2, 100), blk, 0, stream>>>(h, WT_a1, nullptr, a2,
        attbias, attbn_g, attbn_b, nullptr, nullptr, nullptr, 256, 256, 0);
    mfma_gemm_k<0, 0, 400, 0><<<dim3(2, 100), blk, 0, stream>>>(a2, WT_a2, att_b2, logits,
        nullptr, nullptr, nullptr, nullptr, nullptr, nullptr, 256, 256, 0);
    softmax_part_k<<<dim3(32, 8), blk, 0, stream>>>(logits, h, aux_len, smpart);
    softmax_comb_k<<<dim3(32), blk, 0, stream>>>(smpart, bn5_g, bn5_b, e5);
    emb_k<<<dim3(32), dim3(1024), 0, stream>>>(e5, fc6_w, fc6_b, bn6_g, bn6_b, cls_w, cls_b,
                                               out_cls, embG);
    arnvec_k<<<dim3(128), blk, 0, stream>>>(embG, arn_w2, arn_b, arnvec);
    arn_fused_k<<<dim3(250), dim3(512), 0, stream>>>(o0b, WT_arn, WT_out, out_b, arnvec, y);
    ola_k<<<dim3(20000), blk, 0, stream>>>(y, out_sig);
}